// Round 4
// baseline (280.069 us; speedup 1.0000x reference)
//
#include <hip/hip_runtime.h>
#include <hip/hip_bf16.h>

// ---------- constants ----------
#define D_MODEL   1024
#define D_STATE   16
#define D_CONV    4
#define HEADDIM   64
#define NHEADS    32
#define D_INNER   2048
#define CONV_DIM  2080           // D_INNER + 2*D_STATE
#define D_IN_PROJ 4160           // 2*D_INNER + 2*D_STATE + NHEADS
#define NPAD      4224           // D_IN_PROJ padded to x128
#define BATCH     4
#define SEQLEN    2048
#define MROWS     (BATCH*SEQLEN) // 8192
#define QCHUNK    64
#define NCHUNK    (SEQLEN/QCHUNK) // 32
#define DT_COL    (2*D_INNER + 2*D_STATE)   // 4128: dt raw column in zx

// weight pre-scale (better e4m3 utilization); inverses folded into epilogues
#define WSCALE    16.f
#define YSCALE    64.f

// ---------- helpers ----------
__device__ __forceinline__ unsigned short f2b(float f) {
    union { float f; unsigned int u; } v; v.f = f;
    unsigned int r = (v.u + 0x7FFFu + ((v.u >> 16) & 1u)) >> 16;
    return (unsigned short)r;
}
__device__ __forceinline__ float b2f(unsigned short h) {
    union { unsigned int u; float f; } v; v.u = ((unsigned int)h) << 16;
    return v.f;
}
__device__ __forceinline__ unsigned char f2fp8(float f) {
    return (unsigned char)(__builtin_amdgcn_cvt_pk_fp8_f32(f, 0.f, 0, false) & 0xFF);
}

typedef __attribute__((ext_vector_type(8))) short bf16x8;
typedef __attribute__((ext_vector_type(4))) float f32x4;
typedef __attribute__((ext_vector_type(4))) int   i32x4;
typedef __attribute__((ext_vector_type(8))) int   i32x8;

__device__ __forceinline__ i32x8 cat8(i32x4 a, i32x4 b) {
    i32x8 r;
    r[0] = a[0]; r[1] = a[1]; r[2] = a[2]; r[3] = a[3];
    r[4] = b[0]; r[5] = b[1]; r[6] = b[2]; r[7] = b[3];
    return r;
}

// ---------- 1. cast fp32 -> fp8 e4m3 ----------
__global__ void cast_f32_fp8(const float* __restrict__ in, unsigned char* __restrict__ out, int n) {
    int i = (blockIdx.x * blockDim.x + threadIdx.x) * 4;
    if (i >= n) return;
    float4 v = *(const float4*)&in[i];
    int p = __builtin_amdgcn_cvt_pk_fp8_f32(v.x, v.y, 0, false);
    p = __builtin_amdgcn_cvt_pk_fp8_f32(v.z, v.w, p, true);
    *(unsigned int*)&out[i] = (unsigned int)p;
}

// ---------- 2. both weight transposes -> fp8 (x WSCALE, W_out also x norm_w) ----------
__global__ void transpose_both(const float* __restrict__ W_in, unsigned char* __restrict__ winT,
                               const float* __restrict__ W_out, unsigned char* __restrict__ woutT,
                               const float* __restrict__ norm_w) {
    __shared__ float tile[64][65];
    int bid = blockIdx.x;
    const float* W; unsigned char* WT; const float* kscale;
    int K, N, bx, by;
    if (bid < 1056) { W = W_in;  WT = winT;  kscale = nullptr; K = 1024; N = 4160; bx = bid % 66; by = bid / 66; }
    else { bid -= 1056; W = W_out; WT = woutT; kscale = norm_w; K = 2048; N = 1024; bx = bid % 16; by = bid / 16; }
    int n0 = bx * 64, k0 = by * 64;
    int tx = threadIdx.x & 63, ty = threadIdx.x >> 6;
    #pragma unroll
    for (int i = 0; i < 16; i++) {
        int r = ty * 16 + i;
        int n = n0 + tx;
        float v = (n < N) ? W[(size_t)(k0 + r) * N + n] : 0.f;
        tile[r][tx] = v;
    }
    __syncthreads();
    float ks = WSCALE * (kscale ? kscale[k0 + tx] : 1.f);
    #pragma unroll
    for (int i = 0; i < 16; i++) {
        int r = ty * 16 + i;
        WT[(size_t)(n0 + r) * K + k0 + tx] = f2fp8(tile[tx][r] * ks);
    }
}

// ---------- 3. fp8 MFMA GEMM (MX-scaled K=128), 128x128 tile ----------
// Single-buffered 32 KB LDS (preserves ~4-5 blocks/CU TLP — the m132 lesson:
// LDS footprint is the occupancy currency). ILP added via REGISTER prefetch
// (T14 issue-early/write-late): global loads for tile t+1 issue before tile
// t's MFMAs and land during the ~550-cycle compute span; only the cheap
// ds_writes sit between the two barriers.
template <int EPI>
__global__ __launch_bounds__(256)
void gemm_fp8(const unsigned char* __restrict__ A, const unsigned char* __restrict__ B,
              int K, int N, unsigned short* __restrict__ Cb,
              float* __restrict__ Cf, const float* __restrict__ xres,
              const float* __restrict__ ls, const float* __restrict__ rs) {
    __shared__ unsigned char lds_a[128 * 128];
    __shared__ unsigned char lds_b[128 * 128];
    const int tid  = threadIdx.x;
    const int wave = tid >> 6;
    const int lane = tid & 63;
    const int bid = blockIdx.x;
    const int xcd = bid & 7, g = bid >> 3;
    const int bm = xcd * 8 + (g & 7);    // 8 A-panels pinned per XCD (1 MB in L2)
    const int bn = g >> 3;
    const int wm = wave >> 1, wn = wave & 1;

    f32x4 acc[4][4];
    #pragma unroll
    for (int i = 0; i < 4; i++)
        #pragma unroll
        for (int j = 0; j < 4; j++) acc[i][j] = (f32x4){0.f, 0.f, 0.f, 0.f};

    // pre-swizzled global source (same image global_load_lds produced):
    // lane writes its 16B to ldsbase + j*32*128 + lane*16
    const int srow = lane >> 3;
    const int sseg = (lane & 7) ^ srow;
    const unsigned char* gA0 = A + (size_t)(bm * 128 + wave * 8 + srow) * K + sseg * 16;
    const unsigned char* gB0 = B + (size_t)(bn * 128 + wave * 8 + srow) * K + sseg * 16;
    const int ldsbase = wave * 8 * 128;
    const int wofs = ldsbase + lane * 16;

    const int lm = lane & 15, q = lane >> 4;

    i32x4 ra[4], rb[4];
    // prologue: tile 0 -> regs -> LDS
    #pragma unroll
    for (int j = 0; j < 4; j++) {
        ra[j] = *(const i32x4*)(gA0 + (size_t)(j * 32) * K);
        rb[j] = *(const i32x4*)(gB0 + (size_t)(j * 32) * K);
    }
    #pragma unroll
    for (int j = 0; j < 4; j++) {
        *(i32x4*)&lds_a[wofs + j * 32 * 128] = ra[j];
        *(i32x4*)&lds_b[wofs + j * 32 * 128] = rb[j];
    }
    __syncthreads();

    const int NT = K >> 7;
    for (int t = 0; t < NT; ++t) {
        // issue next tile's loads FIRST: they land under the MFMA span
        if (t + 1 < NT) {
            #pragma unroll
            for (int j = 0; j < 4; j++) {
                ra[j] = *(const i32x4*)(gA0 + (t + 1) * 128 + (size_t)(j * 32) * K);
                rb[j] = *(const i32x4*)(gB0 + (t + 1) * 128 + (size_t)(j * 32) * K);
            }
        }

        i32x8 af[4], bfr[4];
        #pragma unroll
        for (int i = 0; i < 4; i++) {
            int r = wm * 64 + i * 16 + lm;
            int s0 = ((2 * q) ^ (r & 7)) * 16, s1 = ((2 * q + 1) ^ (r & 7)) * 16;
            af[i] = cat8(*(const i32x4*)&lds_a[r * 128 + s0],
                         *(const i32x4*)&lds_a[r * 128 + s1]);
        }
        #pragma unroll
        for (int j = 0; j < 4; j++) {
            int r = wn * 64 + j * 16 + lm;
            int s0 = ((2 * q) ^ (r & 7)) * 16, s1 = ((2 * q + 1) ^ (r & 7)) * 16;
            bfr[j] = cat8(*(const i32x4*)&lds_b[r * 128 + s0],
                          *(const i32x4*)&lds_b[r * 128 + s1]);
        }
        #pragma unroll
        for (int i = 0; i < 4; i++)
            #pragma unroll
            for (int j = 0; j < 4; j++)
                acc[i][j] = __builtin_amdgcn_mfma_scale_f32_16x16x128_f8f6f4(
                    af[i], bfr[j], acc[i][j], 0, 0,
                    0, 0x7F7F7F7F, 0, 0x7F7F7F7F);

        __syncthreads();                 // all waves done reading the buffer
        if (t + 1 < NT) {
            #pragma unroll
            for (int j = 0; j < 4; j++) {   // regs ready (landed during MFMAs)
                *(i32x4*)&lds_a[wofs + j * 32 * 128] = ra[j];
                *(i32x4*)&lds_b[wofs + j * 32 * 128] = rb[j];
            }
            __syncthreads();             // writes visible
        }
    }

    const int row0 = bm * 128 + wm * 64;
    const int col0 = bn * 128 + wn * 64;
    const int lq = (lane >> 4) * 4;
    #pragma unroll
    for (int i = 0; i < 4; i++) {
        #pragma unroll
        for (int j = 0; j < 4; j++) {
            #pragma unroll
            for (int r = 0; r < 4; r++) {
                int gr = row0 + i * 16 + lq + r;
                int gc = col0 + j * 16 + lm;
                float v = acc[i][j][r];
                if (EPI == 0) {
                    Cb[(size_t)gr * N + gc] = f2b(v * (1.f / WSCALE));
                } else {
                    size_t idx = (size_t)gr * 1024 + gc;
                    Cf[idx] = xres[idx] + v * ls[gc] * rs[gr] * (1.f / (WSCALE * YSCALE));
                }
            }
        }
    }
}

// ---------- 5a. conv + chunk-local state; persists conv(X)^T, conv(B/C), dt/cd/scale ----------
__global__ __launch_bounds__(256)
void ssd_hcomp(const unsigned short* __restrict__ zx, const float* __restrict__ dt_bias,
               const float* __restrict__ conv_w, const float* __restrict__ conv_b,
               const float* __restrict__ A_log,
               float* __restrict__ hbuf, float* __restrict__ pbuf,
               unsigned short* __restrict__ xTg, unsigned short* __restrict__ bcg,
               float* __restrict__ scA) {
    __shared__ unsigned short sXraw[67 * 64];
    __shared__ unsigned short sBCraw[67 * 32];
    __shared__ unsigned short sXT[64 * 72];
    __shared__ unsigned short sBC[64 * 32];
    __shared__ unsigned short sBwT[16 * 72];
    __shared__ float sdt[64], scd[64];

    const int blk = blockIdx.x;
    const int c  = blk & 31;
    const int h  = (blk >> 5) & 31;
    const int b  = blk >> 10;
    const int bh = blk >> 5;
    const int row0 = b * SEQLEN + c * QCHUNK;
    const int batch0 = b * SEQLEN;

    const int t    = threadIdx.x;
    const int w    = t >> 6;
    const int lane = t & 63;
    const int lm   = lane & 15;
    const int lq8  = (lane >> 4) * 8;
    const int lq4  = (lane >> 4) * 4;
    const float Ah = -__expf(A_log[h]);

    // ---- phase 1: halo staging + dt softplus/prefix ----
    for (int i = t; i < 536; i += 256) {
        int r = i >> 3, seg = i & 7;
        int gr = row0 - 3 + r;
        int4 v = (gr >= batch0) ? *(const int4*)&zx[(size_t)gr * NPAD + D_INNER + h * 64 + seg * 8]
                                : (int4){0, 0, 0, 0};
        *(int4*)&sXraw[r * 64 + seg * 8] = v;
    }
    for (int i = t; i < 268; i += 256) {
        int r = i >> 2, seg = i & 3;
        int gr = row0 - 3 + r;
        int4 v = (gr >= batch0) ? *(const int4*)&zx[(size_t)gr * NPAD + 2 * D_INNER + seg * 8]
                                : (int4){0, 0, 0, 0};
        *(int4*)&sBCraw[r * 32 + seg * 8] = v;
    }
    if (t < 64) {
        float raw = b2f(zx[(size_t)(row0 + t) * NPAD + DT_COL + h]) + dt_bias[h];
        float dtv = (raw > 20.f) ? raw : log1pf(__expf(raw));
        float v = dtv;
        #pragma unroll
        for (int o = 1; o < 64; o <<= 1) {
            float u = __shfl_up(v, o, 64);
            if (t >= o) v += u;
        }
        sdt[t] = dtv;
        scd[t] = v;
        float sc = __expf(Ah * v);
        float* scrow = &scA[(size_t)(bh * NCHUNK + c) * 192];
        scrow[t] = dtv; scrow[64 + t] = v; scrow[128 + t] = sc;
        if (t == 63) pbuf[bh * NCHUNK + c] = sc;
    }
    __syncthreads();

    // ---- phase 2: conv + silu (sliding window) ----
    {   // X: thread owns column p, 16 s values
        const int p = t & 63, sblk = (t >> 6) * 16;
        const int ch = h * 64 + p;
        const float4 cw = *(const float4*)&conv_w[ch * 4];
        const float cb = conv_b[ch];
        float x0 = b2f(sXraw[(sblk + 0) * 64 + p]);
        float x1 = b2f(sXraw[(sblk + 1) * 64 + p]);
        float x2 = b2f(sXraw[(sblk + 2) * 64 + p]);
        #pragma unroll
        for (int i = 0; i < 16; i++) {
            float x3 = b2f(sXraw[(sblk + i + 3) * 64 + p]);
            float acc = cb + cw.x * x0 + cw.y * x1 + cw.z * x2 + cw.w * x3;
            float sv = acc / (1.f + __expf(-acc));
            sXT[p * 72 + sblk + i] = f2b(sv);
            x0 = x1; x1 = x2; x2 = x3;
        }
    }
    {   // B/C: thread owns channel ch32, 8 s values; ch32<16 also writes weighted Bw^T
        const int ch32 = t & 31, s0 = (t >> 5) * 8;
        const int ch = D_INNER + ch32;
        const float4 cw = *(const float4*)&conv_w[ch * 4];
        const float cb = conv_b[ch];
        const float cdl = scd[63];
        float x0 = b2f(sBCraw[(s0 + 0) * 32 + ch32]);
        float x1 = b2f(sBCraw[(s0 + 1) * 32 + ch32]);
        float x2 = b2f(sBCraw[(s0 + 2) * 32 + ch32]);
        #pragma unroll
        for (int i = 0; i < 8; i++) {
            int s = s0 + i;
            float x3 = b2f(sBCraw[(s + 3) * 32 + ch32]);
            float acc = cb + cw.x * x0 + cw.y * x1 + cw.z * x2 + cw.w * x3;
            float sv = acc / (1.f + __expf(-acc));
            sBC[s * 32 + ch32] = f2b(sv);
            if (ch32 < 16) {
                float wgt = sdt[s] * __expf(Ah * (cdl - scd[s]));
                sBwT[ch32 * 72 + s] = f2b(sv * wgt);
            }
            x0 = x1; x1 = x2; x2 = x3;
        }
    }
    __syncthreads();

    // ---- phase 3: h_local = Bw^T X ----
    f32x4 hacc = (f32x4){0.f, 0.f, 0.f, 0.f};
    #pragma unroll
    for (int ks = 0; ks < 2; ks++) {
        bf16x8 af = *(const bf16x8*)&sBwT[lm * 72 + ks * 32 + lq8];
        bf16x8 bf_ = *(const bf16x8*)&sXT[(w * 16 + lm) * 72 + ks * 32 + lq8];
        hacc = __builtin_amdgcn_mfma_f32_16x16x32_bf16(af, bf_, hacc, 0, 0, 0);
    }
    #pragma unroll
    for (int r = 0; r < 4; r++)
        hbuf[(size_t)(bh * NCHUNK + c) * 1024 + (lq4 + r) * 64 + (w * 16 + lm)] = hacc[r];

    // ---- phase 4: persist conv outputs ----
    #pragma unroll
    for (int it = 0; it < 2; it++) {
        int idx = t + it * 256;          // 512 int4: row p = idx>>3, seg = idx&7
        int p = idx >> 3, seg = idx & 7;
        *(int4*)&xTg[(size_t)(bh * 64 + p) * SEQLEN + c * 64 + seg * 8] =
            *(const int4*)&sXT[p * 72 + seg * 8];
    }
    if (h == 0) {                        // bcg: 64 rows x 32 ch = 256 int4
        int s = t >> 2, seg = t & 3;
        *(int4*)&bcg[(size_t)(b * SEQLEN + c * 64 + s) * 32 + seg * 8] =
            *(const int4*)&sBC[s * 32 + seg * 8];
    }
}

// ---------- 5b. inter-chunk state scan: register-prefetched ----------
__global__ __launch_bounds__(1024)
void ssd_state_scan(float* __restrict__ hbuf, const float* __restrict__ pbuf) {
    int bh = blockIdx.x;
    int t = threadIdx.x;
    __shared__ float sP[NCHUNK];
    if (t < NCHUNK) sP[t] = pbuf[bh * NCHUNK + t];
    __syncthreads();
    size_t base = (size_t)bh * NCHUNK * 1024 + t;
    float v[NCHUNK];
    #pragma unroll
    for (int c = 0; c < NCHUNK; c++) v[c] = hbuf[base + (size_t)c * 1024];
    float carry = 0.f;
    #pragma unroll
    for (int c = 0; c < NCHUNK; c++) {
        float tmp = v[c];
        v[c] = carry;
        carry = tmp + sP[c] * carry;
    }
    #pragma unroll
    for (int c = 0; c < NCHUNK; c++) hbuf[base + (size_t)c * 1024] = v[c];
}

// ---------- 5c. y kernel (pure MFMA + epilogue): yq = fp8(YSCALE*(M.X + scale*(C.h_in))*silu(z)) ----------
// D*x folded into M's diagonal.
__global__ __launch_bounds__(256)
void ssd_yfused(const unsigned short* __restrict__ zx,
                const unsigned short* __restrict__ xTg, const unsigned short* __restrict__ bcg,
                const float* __restrict__ scA,
                const float* __restrict__ A_log, const float* __restrict__ D_param,
                const float* __restrict__ hbuf,
                unsigned char* __restrict__ y, float* __restrict__ ssq) {
    __shared__ unsigned short sXT[64 * 72];
    __shared__ unsigned short sM[64 * 72];
    __shared__ unsigned short sB[64 * 32];
    __shared__ unsigned short sC[64 * 32];
    __shared__ unsigned short sZ[64 * 64];
    __shared__ unsigned short sHT[64 * 40];
    __shared__ float sdt[64], scd[64], sSc[64];

    const int blk = blockIdx.x;
    const int c  = blk & 31;
    const int h  = (blk >> 5) & 31;
    const int b  = blk >> 10;
    const int bh = blk >> 5;
    const int row0 = b * SEQLEN + c * QCHUNK;

    const int t    = threadIdx.x;
    const int w    = t >> 6;
    const int lane = t & 63;
    const int lm   = lane & 15;
    const int lq8  = (lane >> 4) * 8;
    const int lq4  = (lane >> 4) * 4;
    const float Ah = -__expf(A_log[h]);

    // ---- staging (all vector loads) ----
    #pragma unroll
    for (int it = 0; it < 2; it++) {
        int idx = t + it * 256;          // X^T: 512 int4
        int p = idx >> 3, seg = idx & 7;
        *(int4*)&sXT[p * 72 + seg * 8] =
            *(const int4*)&xTg[(size_t)(bh * 64 + p) * SEQLEN + c * 64 + seg * 8];
    }
    #pragma unroll
    for (int it = 0; it < 2; it++) {
        int idx = t + it * 256;          // z: 512 int4
        int s = idx >> 3, seg = idx & 7;
        *(int4*)&sZ[s * 64 + seg * 8] =
            *(const int4*)&zx[(size_t)(row0 + s) * NPAD + h * 64 + seg * 8];
    }
    {                                    // B/C: 256 int4
        int s = t >> 2, seg = t & 3;
        int4 v = *(const int4*)&bcg[(size_t)(b * SEQLEN + c * 64 + s) * 32 + seg * 8];
        if (seg < 2) *(int4*)&sB[s * 32 + seg * 8] = v;
        else         *(int4*)&sC[s * 32 + (seg - 2) * 8] = v;
    }
    {                                    // h_in -> sHT [p][n] bf16
        size_t hb = (size_t)(bh * NCHUNK + c) * 1024 + (size_t)t * 4;
        float4 hv = *(const float4*)&hbuf[hb];
        int n = t >> 4;
        int p0 = (t * 4) & 63;
        sHT[(p0 + 0) * 40 + n] = f2b(hv.x);
        sHT[(p0 + 1) * 40 + n] = f2b(hv.y);
        sHT[(p0 + 2) * 40 + n] = f2b(hv.z);
        sHT[(p0 + 3) * 40 + n] = f2b(hv.w);
    }
    if (t < 64) {                        // pads
        *(int4*)&sB[t * 32 + 16] = (int4){0, 0, 0, 0};
        *(int4*)&sB[t * 32 + 24] = (int4){0, 0, 0, 0};
        *(int4*)&sC[t * 32 + 16] = (int4){0, 0, 0, 0};
        *(int4*)&sC[t * 32 + 24] = (int4){0, 0, 0, 0};
        *(int4*)&sHT[t * 40 + 16] = (int4){0, 0, 0, 0};
        *(int4*)&sHT[t * 40 + 24] = (int4){0, 0, 0, 0};
    }
    if (t < 192) {                       // dt / cd / scale
        float v = scA[(size_t)(bh * NCHUNK + c) * 192 + t];
        if (t < 64) sdt[t] = v;
        else if (t < 128) scd[t - 64] = v;
        else sSc[t - 128] = v;
    }
    __syncthreads();

    // ---- S = C * B^T (lower-triangular blocks) ----
    f32x4 sacc[4];
    {
        bf16x8 cfrag = *(const bf16x8*)&sC[(w * 16 + lm) * 32 + lq8];
        #pragma unroll
        for (int sb = 0; sb < 4; sb++) {
            if (sb <= w) {
                bf16x8 bfrag = *(const bf16x8*)&sB[(sb * 16 + lm) * 32 + lq8];
                sacc[sb] = __builtin_amdgcn_mfma_f32_16x16x32_bf16(
                    cfrag, bfrag, (f32x4){0.f, 0.f, 0.f, 0.f}, 0, 0, 0);
            }
        }
    }
    // ---- M[t][s] with D on the diagonal ----
    const float Dh = D_param[h];
    #pragma unroll
    for (int sb = 0; sb < 4; sb++) {
        int sp = sb * 16 + lm;
        if (sb > w) {
            #pragma unroll
            for (int r = 0; r < 4; r++) sM[(w * 16 + lq4 + r) * 72 + sp] = 0;
        } else {
            float dts = sdt[sp], cds = scd[sp];
            #pragma unroll
            for (int r = 0; r < 4; r++) {
                int tp = w * 16 + lq4 + r;
                float m = 0.f;
                if (sb < w || sp <= tp) {
                    m = sacc[sb][r] * dts * __expf(Ah * (scd[tp] - cds));
                    if (sp == tp) m += Dh;
                }
                sM[tp * 72 + sp] = f2b(m);
            }
        }
    }

    // ---- Y1 = M * X ----
    f32x4 yacc[4];
    #pragma unroll
    for (int pb = 0; pb < 4; pb++) yacc[pb] = (f32x4){0.f, 0.f, 0.f, 0.f};
    #pragma unroll
    for (int ks = 0; ks < 2; ks++) {
        if (ks == 1 && w < 2) continue;
        bf16x8 af = *(const bf16x8*)&sM[(w * 16 + lm) * 72 + ks * 32 + lq8];
        #pragma unroll
        for (int pb = 0; pb < 4; pb++) {
            bf16x8 bf_ = *(const bf16x8*)&sXT[(pb * 16 + lm) * 72 + ks * 32 + lq8];
            yacc[pb] = __builtin_amdgcn_mfma_f32_16x16x32_bf16(af, bf_, yacc[pb], 0, 0, 0);
        }
    }
    // ---- Y2 = C * h_in^T ----
    f32x4 acc2[4];
    {
        bf16x8 cf2 = *(const bf16x8*)&sC[(w * 16 + lm) * 32 + lq8];
        #pragma unroll
        for (int pb = 0; pb < 4; pb++) {
            bf16x8 hf = *(const bf16x8*)&sHT[(pb * 16 + lm) * 40 + lq8];
            acc2[pb] = __builtin_amdgcn_mfma_f32_16x16x32_bf16(
                cf2, hf, (f32x4){0.f, 0.f, 0.f, 0.f}, 0, 0, 0);
        }
    }

    // ---- epilogue: z-gate, fp8 store, ssq partials ----
    #pragma unroll
    for (int r = 0; r < 4; r++) {
        const int tp = w * 16 + lq4 + r;
        const size_t yrow = (size_t)(row0 + tp) * D_INNER + h * 64;
        float ssr = 0.f;
        #pragma unroll
        for (int pb = 0; pb < 4; pb++) {
            int pp = pb * 16 + lm;
            float val = yacc[pb][r] + sSc[tp] * acc2[pb][r];
            float zv = b2f(sZ[tp * 64 + pp]);
            float yg = val * (zv / (1.f + __expf(-zv)));
            ssr += yg * yg;
            y[yrow + pp] = f2fp8(yg * YSCALE);
        }
        ssr += __shfl_xor(ssr, 1, 16);
        ssr += __shfl_xor(ssr, 2, 16);
        ssr += __shfl_xor(ssr, 4, 16);
        ssr += __shfl_xor(ssr, 8, 16);
        if (lm == 0)
            ssq[(size_t)(row0 + tp) * NHEADS + h] = ssr;
    }
}

// ---------- 5d. per-row rsqrt scale ----------
__global__ __launch_bounds__(256)
void rowscale_kernel(const float* __restrict__ ssq, float* __restrict__ rs) {
    int row = blockIdx.x * 256 + threadIdx.x;
    const float4* p = (const float4*)&ssq[(size_t)row * NHEADS];
    float s = 0.f;
    #pragma unroll
    for (int i = 0; i < 8; i++) {
        float4 v = p[i];
        s += v.x + v.y + v.z + v.w;
    }
    rs[row] = rsqrtf(s * (1.f / D_INNER) + 1e-5f);
}

// ---------- launcher ----------
extern "C" void kernel_launch(void* const* d_in, const int* in_sizes, int n_in,
                              void* d_out, int out_size, void* d_ws, size_t ws_size,
                              hipStream_t stream) {
    const float* x        = (const float*)d_in[0];
    const float* W_in     = (const float*)d_in[1];
    const float* conv_w   = (const float*)d_in[2];
    const float* conv_b   = (const float*)d_in[3];
    const float* dt_bias  = (const float*)d_in[4];
    const float* A_log    = (const float*)d_in[5];
    const float* D_param  = (const float*)d_in[6];
    const float* norm_w   = (const float*)d_in[7];
    const float* W_out    = (const float*)d_in[8];
    const float* ls       = (const float*)d_in[9];
    float* out = (float*)d_out;

    char* ws = (char*)d_ws;
    size_t off = 0;
    unsigned char*  x_f8  = (unsigned char*)(ws + off);  off += (size_t)MROWS * D_MODEL;       // 8.4 MB
    unsigned char*  winT  = (unsigned char*)(ws + off);  off += (size_t)NPAD * D_MODEL;        // 4.3 MB
    unsigned char*  woutT = (unsigned char*)(ws + off);  off += (size_t)D_MODEL * D_INNER;     // 2.1 MB
    unsigned short* zx    = (unsigned short*)(ws + off); off += (size_t)MROWS * NPAD * 2;      // 69.2 MB
    float*          pbuf  = (float*)(ws + off);          off += (size_t)BATCH * NHEADS * NCHUNK * 4;
    unsigned char*  yb    = (unsigned char*)(ws + off);  off += (size_t)MROWS * D_INNER;       // 16.8 MB
    float*          ssq   = (float*)(ws + off);          off += (size_t)MROWS * NHEADS * 4;    // 1 MB
    float*          rsb   = (float*)(ws + off);          off += (size_t)MROWS * 4;
    float*          hbuf  = (float*)(ws + off);          off += (size_t)BATCH * NHEADS * NCHUNK * 1024 * 4; // 16.8 MB
    unsigned short* xTg   = (unsigned short*)(ws + off); off += (size_t)MROWS * D_INNER * 2;   // 33.5 MB
    unsigned short* bcg   = (unsigned short*)(ws + off); off += (size_t)MROWS * 32 * 2;        // 0.5 MB
    float*          scA   = (float*)(ws + off);          off += (size_t)BATCH * NHEADS * NCHUNK * 192 * 4; // 3.1 MB

    cast_f32_fp8<<<(MROWS * D_MODEL) / 1024, 256, 0, stream>>>(x, x_f8, MROWS * D_MODEL);
    transpose_both<<<1568, 256, 0, stream>>>(W_in, winT, W_out, woutT, norm_w);
    gemm_fp8<0><<<(NPAD / 128) * 64, 256, 0, stream>>>(
        x_f8, winT, D_MODEL, NPAD, zx, nullptr, nullptr, nullptr, nullptr);
    ssd_hcomp<<<BATCH * NHEADS * NCHUNK, 256, 0, stream>>>(
        zx, dt_bias, conv_w, conv_b, A_log, hbuf, pbuf, xTg, bcg, scA);
    ssd_state_scan<<<BATCH * NHEADS, 1024, 0, stream>>>(hbuf, pbuf);
    ssd_yfused<<<BATCH * NHEADS * NCHUNK, 256, 0, stream>>>(
        zx, xTg, bcg, scA, A_log, D_param, hbuf, yb, ssq);
    rowscale_kernel<<<MROWS / 256, 256, 0, stream>>>(ssq, rsb);
    gemm_fp8<1><<<(D_MODEL / 128) * 64, 256, 0, stream>>>(
        yb, woutT, D_INNER, D_MODEL, nullptr, out, x, ls, rsb);
}

// Round 5
// 269.556 us; speedup vs baseline: 1.0390x; 1.0390x over previous
//
#include <hip/hip_runtime.h>
#include <hip/hip_bf16.h>

// ---------- constants ----------
#define D_MODEL   1024
#define D_STATE   16
#define D_CONV    4
#define HEADDIM   64
#define NHEADS    32
#define D_INNER   2048
#define CONV_DIM  2080           // D_INNER + 2*D_STATE
#define D_IN_PROJ 4160           // 2*D_INNER + 2*D_STATE + NHEADS
#define NPAD      4224           // D_IN_PROJ padded to x128
#define BATCH     4
#define SEQLEN    2048
#define MROWS     (BATCH*SEQLEN) // 8192
#define QCHUNK    64
#define NCHUNK    (SEQLEN/QCHUNK) // 32
#define DT_COL    (2*D_INNER + 2*D_STATE)   // 4128: dt raw column in zx

// weight pre-scale (better e4m3 utilization); inverses folded into epilogues
#define WSCALE    16.f
#define YSCALE    64.f

// ---------- helpers ----------
__device__ __forceinline__ unsigned short f2b(float f) {
    union { float f; unsigned int u; } v; v.f = f;
    unsigned int r = (v.u + 0x7FFFu + ((v.u >> 16) & 1u)) >> 16;
    return (unsigned short)r;
}
__device__ __forceinline__ float b2f(unsigned short h) {
    union { unsigned int u; float f; } v; v.u = ((unsigned int)h) << 16;
    return v.f;
}
__device__ __forceinline__ unsigned char f2fp8(float f) {
    return (unsigned char)(__builtin_amdgcn_cvt_pk_fp8_f32(f, 0.f, 0, false) & 0xFF);
}

typedef __attribute__((ext_vector_type(8))) short bf16x8;
typedef __attribute__((ext_vector_type(4))) float f32x4;
typedef __attribute__((ext_vector_type(4))) int   i32x4;
typedef __attribute__((ext_vector_type(8))) int   i32x8;

__device__ __forceinline__ i32x8 cat8(i32x4 a, i32x4 b) {
    i32x8 r;
    r[0] = a[0]; r[1] = a[1]; r[2] = a[2]; r[3] = a[3];
    r[4] = b[0]; r[5] = b[1]; r[6] = b[2]; r[7] = b[3];
    return r;
}

__device__ __forceinline__ void async_copy16b(const unsigned char* g, unsigned char* l) {
    __builtin_amdgcn_global_load_lds(
        (const __attribute__((address_space(1))) void*)g,
        (__attribute__((address_space(3))) void*)l, 16, 0, 0);
}

// ---------- 1+2 fused: cast fp32->fp8 AND both weight transposes ----------
__global__ __launch_bounds__(256)
void pre_kernel(const float* __restrict__ x, unsigned char* __restrict__ x_f8,
                const float* __restrict__ W_in, unsigned char* __restrict__ winT,
                const float* __restrict__ W_out, unsigned char* __restrict__ woutT,
                const float* __restrict__ norm_w) {
    __shared__ float tile[64][65];
    int bid = blockIdx.x;
    if (bid < 8192) {                    // cast path: 8192 blocks x 1024 elems
        int i = (bid * 256 + threadIdx.x) * 4;
        float4 v = *(const float4*)&x[i];
        int p = __builtin_amdgcn_cvt_pk_fp8_f32(v.x, v.y, 0, false);
        p = __builtin_amdgcn_cvt_pk_fp8_f32(v.z, v.w, p, true);
        *(unsigned int*)&x_f8[i] = (unsigned int)p;
        return;
    }
    bid -= 8192;                         // transpose path: 1568 blocks
    const float* W; unsigned char* WT; const float* kscale;
    int K, N, bx, by;
    if (bid < 1056) { W = W_in;  WT = winT;  kscale = nullptr; K = 1024; N = 4160; bx = bid % 66; by = bid / 66; }
    else { bid -= 1056; W = W_out; WT = woutT; kscale = norm_w; K = 2048; N = 1024; bx = bid % 16; by = bid / 16; }
    int n0 = bx * 64, k0 = by * 64;
    int tx = threadIdx.x & 63, ty = threadIdx.x >> 6;
    #pragma unroll
    for (int i = 0; i < 16; i++) {
        int r = ty * 16 + i;
        int n = n0 + tx;
        float v = (n < N) ? W[(size_t)(k0 + r) * N + n] : 0.f;
        tile[r][tx] = v;
    }
    __syncthreads();
    float ks = WSCALE * (kscale ? kscale[k0 + tx] : 1.f);
    #pragma unroll
    for (int i = 0; i < 16; i++) {
        int r = ty * 16 + i;
        WT[(size_t)(n0 + r) * K + k0 + tx] = f2fp8(tile[tx][r] * ks);
    }
}

// ---------- 3. fp8 MFMA GEMM (MX-scaled K=128), BMx(NF*32) tile ----------
// EXACT baseline structure (single-buffered, global_load_lds, serial K-loop,
// per-XCD-pinned A panels): r1/r3/r4 proved every ILP scheme here loses to
// multi-block TLP. NF=4 -> 128x128 (in-proj, byte-identical to the 47.4 us
// baseline); NF=2 -> 128x64 (out-proj: doubles grid to 1024 = 4 blocks/CU,
// fixing its TLP starvation). EPI==1 additionally fuses the per-row rsqrt
// (old rowscale_kernel) into the epilogue, reusing lds_a after the K-loop.
template <int EPI, int NF>
__global__ __launch_bounds__(256)
void gemm_fp8(const unsigned char* __restrict__ A, const unsigned char* __restrict__ B,
              int K, int N, unsigned short* __restrict__ Cb,
              float* __restrict__ Cf, const float* __restrict__ xres,
              const float* __restrict__ ls, const float* __restrict__ ssq) {
    constexpr int BN = NF * 32;
    __shared__ unsigned char lds_a[128 * 128];
    __shared__ unsigned char lds_b[BN * 128];
    const int tid  = threadIdx.x;
    const int wave = tid >> 6;
    const int lane = tid & 63;
    const int bid = blockIdx.x;
    const int xcd = bid & 7, g = bid >> 3;
    const int bm = xcd * 8 + (g & 7);    // 8 A-panels pinned per XCD
    const int bn = g >> 3;
    const int wm = wave >> 1, wn = wave & 1;

    f32x4 acc[4][NF];
    #pragma unroll
    for (int i = 0; i < 4; i++)
        #pragma unroll
        for (int j = 0; j < NF; j++) acc[i][j] = (f32x4){0.f, 0.f, 0.f, 0.f};

    const int srow = lane >> 3;
    const int sseg = (lane & 7) ^ srow;
    const unsigned char* gA0 = A + (size_t)(bm * 128 + wave * 8 + srow) * K + sseg * 16;
    const unsigned char* gB0 = B + (size_t)(bn * BN  + wave * 8 + srow) * K + sseg * 16;
    const int ldsbase = wave * 8 * 128;

    const int lm = lane & 15, q = lane >> 4;

    for (int k0 = 0; k0 < K; k0 += 128) {
        #pragma unroll
        for (int j = 0; j < 4; j++)
            async_copy16b(gA0 + k0 + (size_t)(j * 32) * K, &lds_a[ldsbase + j * 32 * 128]);
        #pragma unroll
        for (int j = 0; j < NF; j++)
            async_copy16b(gB0 + k0 + (size_t)(j * 32) * K, &lds_b[ldsbase + j * 32 * 128]);
        __syncthreads();

        i32x8 af[4], bfr[NF];
        #pragma unroll
        for (int i = 0; i < 4; i++) {
            int r = wm * 64 + i * 16 + lm;
            int s0 = ((2 * q) ^ (r & 7)) * 16, s1 = ((2 * q + 1) ^ (r & 7)) * 16;
            af[i] = cat8(*(const i32x4*)&lds_a[r * 128 + s0],
                         *(const i32x4*)&lds_a[r * 128 + s1]);
        }
        #pragma unroll
        for (int j = 0; j < NF; j++) {
            int r = wn * (NF * 16) + j * 16 + lm;
            int s0 = ((2 * q) ^ (r & 7)) * 16, s1 = ((2 * q + 1) ^ (r & 7)) * 16;
            bfr[j] = cat8(*(const i32x4*)&lds_b[r * 128 + s0],
                          *(const i32x4*)&lds_b[r * 128 + s1]);
        }
        #pragma unroll
        for (int i = 0; i < 4; i++)
            #pragma unroll
            for (int j = 0; j < NF; j++)
                acc[i][j] = __builtin_amdgcn_mfma_scale_f32_16x16x128_f8f6f4(
                    af[i], bfr[j], acc[i][j], 0, 0,
                    0, 0x7F7F7F7F, 0, 0x7F7F7F7F);
        __syncthreads();
    }

    // fused per-row rsqrt scale (old rowscale_kernel), LDS reused after K-loop
    float* srs = (float*)lds_a;
    if constexpr (EPI == 1) {
        if (tid < 128) {
            const float4* p = (const float4*)&ssq[(size_t)(bm * 128 + tid) * NHEADS];
            float s = 0.f;
            #pragma unroll
            for (int i2 = 0; i2 < 8; i2++) {
                float4 v4 = p[i2];
                s += v4.x + v4.y + v4.z + v4.w;
            }
            srs[tid] = rsqrtf(s * (1.f / D_INNER) + 1e-5f);
        }
        __syncthreads();
    }

    const int row0 = bm * 128 + wm * 64;
    const int col0 = bn * BN + wn * (NF * 16);
    const int lq = (lane >> 4) * 4;
    #pragma unroll
    for (int i = 0; i < 4; i++) {
        #pragma unroll
        for (int j = 0; j < NF; j++) {
            #pragma unroll
            for (int r = 0; r < 4; r++) {
                int gr = row0 + i * 16 + lq + r;
                int gc = col0 + j * 16 + lm;
                float v = acc[i][j][r];
                if constexpr (EPI == 0) {
                    Cb[(size_t)gr * N + gc] = f2b(v * (1.f / WSCALE));
                } else {
                    size_t idx = (size_t)gr * 1024 + gc;
                    float rsv = srs[wm * 64 + i * 16 + lq + r];
                    Cf[idx] = xres[idx] + v * ls[gc] * rsv * (1.f / (WSCALE * YSCALE));
                }
            }
        }
    }
}

// ---------- 5a. conv + chunk-local state; persists conv(X)^T, conv(B/C), dt/cd/scale ----------
__global__ __launch_bounds__(256)
void ssd_hcomp(const unsigned short* __restrict__ zx, const float* __restrict__ dt_bias,
               const float* __restrict__ conv_w, const float* __restrict__ conv_b,
               const float* __restrict__ A_log,
               float* __restrict__ hbuf, float* __restrict__ pbuf,
               unsigned short* __restrict__ xTg, unsigned short* __restrict__ bcg,
               float* __restrict__ scA) {
    __shared__ unsigned short sXraw[67 * 64];
    __shared__ unsigned short sBCraw[67 * 32];
    __shared__ unsigned short sXT[64 * 72];
    __shared__ unsigned short sBC[64 * 32];
    __shared__ unsigned short sBwT[16 * 72];
    __shared__ float sdt[64], scd[64];

    const int blk = blockIdx.x;
    const int c  = blk & 31;
    const int h  = (blk >> 5) & 31;
    const int b  = blk >> 10;
    const int bh = blk >> 5;
    const int row0 = b * SEQLEN + c * QCHUNK;
    const int batch0 = b * SEQLEN;

    const int t    = threadIdx.x;
    const int w    = t >> 6;
    const int lane = t & 63;
    const int lm   = lane & 15;
    const int lq8  = (lane >> 4) * 8;
    const int lq4  = (lane >> 4) * 4;
    const float Ah = -__expf(A_log[h]);

    // ---- phase 1: halo staging + dt softplus/prefix ----
    for (int i = t; i < 536; i += 256) {
        int r = i >> 3, seg = i & 7;
        int gr = row0 - 3 + r;
        int4 v = (gr >= batch0) ? *(const int4*)&zx[(size_t)gr * NPAD + D_INNER + h * 64 + seg * 8]
                                : (int4){0, 0, 0, 0};
        *(int4*)&sXraw[r * 64 + seg * 8] = v;
    }
    for (int i = t; i < 268; i += 256) {
        int r = i >> 2, seg = i & 3;
        int gr = row0 - 3 + r;
        int4 v = (gr >= batch0) ? *(const int4*)&zx[(size_t)gr * NPAD + 2 * D_INNER + seg * 8]
                                : (int4){0, 0, 0, 0};
        *(int4*)&sBCraw[r * 32 + seg * 8] = v;
    }
    if (t < 64) {
        float raw = b2f(zx[(size_t)(row0 + t) * NPAD + DT_COL + h]) + dt_bias[h];
        float dtv = (raw > 20.f) ? raw : log1pf(__expf(raw));
        float v = dtv;
        #pragma unroll
        for (int o = 1; o < 64; o <<= 1) {
            float u = __shfl_up(v, o, 64);
            if (t >= o) v += u;
        }
        sdt[t] = dtv;
        scd[t] = v;
        float sc = __expf(Ah * v);
        float* scrow = &scA[(size_t)(bh * NCHUNK + c) * 192];
        scrow[t] = dtv; scrow[64 + t] = v; scrow[128 + t] = sc;
        if (t == 63) pbuf[bh * NCHUNK + c] = sc;
    }
    __syncthreads();

    // ---- phase 2: conv + silu (sliding window) ----
    {   // X: thread owns column p, 16 s values
        const int p = t & 63, sblk = (t >> 6) * 16;
        const int ch = h * 64 + p;
        const float4 cw = *(const float4*)&conv_w[ch * 4];
        const float cb = conv_b[ch];
        float x0 = b2f(sXraw[(sblk + 0) * 64 + p]);
        float x1 = b2f(sXraw[(sblk + 1) * 64 + p]);
        float x2 = b2f(sXraw[(sblk + 2) * 64 + p]);
        #pragma unroll
        for (int i = 0; i < 16; i++) {
            float x3 = b2f(sXraw[(sblk + i + 3) * 64 + p]);
            float acc = cb + cw.x * x0 + cw.y * x1 + cw.z * x2 + cw.w * x3;
            float sv = acc / (1.f + __expf(-acc));
            sXT[p * 72 + sblk + i] = f2b(sv);
            x0 = x1; x1 = x2; x2 = x3;
        }
    }
    {   // B/C: thread owns channel ch32, 8 s values; ch32<16 also writes weighted Bw^T
        const int ch32 = t & 31, s0 = (t >> 5) * 8;
        const int ch = D_INNER + ch32;
        const float4 cw = *(const float4*)&conv_w[ch * 4];
        const float cb = conv_b[ch];
        const float cdl = scd[63];
        float x0 = b2f(sBCraw[(s0 + 0) * 32 + ch32]);
        float x1 = b2f(sBCraw[(s0 + 1) * 32 + ch32]);
        float x2 = b2f(sBCraw[(s0 + 2) * 32 + ch32]);
        #pragma unroll
        for (int i = 0; i < 8; i++) {
            int s = s0 + i;
            float x3 = b2f(sBCraw[(s + 3) * 32 + ch32]);
            float acc = cb + cw.x * x0 + cw.y * x1 + cw.z * x2 + cw.w * x3;
            float sv = acc / (1.f + __expf(-acc));
            sBC[s * 32 + ch32] = f2b(sv);
            if (ch32 < 16) {
                float wgt = sdt[s] * __expf(Ah * (cdl - scd[s]));
                sBwT[ch32 * 72 + s] = f2b(sv * wgt);
            }
            x0 = x1; x1 = x2; x2 = x3;
        }
    }
    __syncthreads();

    // ---- phase 3: h_local = Bw^T X ----
    f32x4 hacc = (f32x4){0.f, 0.f, 0.f, 0.f};
    #pragma unroll
    for (int ks = 0; ks < 2; ks++) {
        bf16x8 af = *(const bf16x8*)&sBwT[lm * 72 + ks * 32 + lq8];
        bf16x8 bf_ = *(const bf16x8*)&sXT[(w * 16 + lm) * 72 + ks * 32 + lq8];
        hacc = __builtin_amdgcn_mfma_f32_16x16x32_bf16(af, bf_, hacc, 0, 0, 0);
    }
    #pragma unroll
    for (int r = 0; r < 4; r++)
        hbuf[(size_t)(bh * NCHUNK + c) * 1024 + (lq4 + r) * 64 + (w * 16 + lm)] = hacc[r];

    // ---- phase 4: persist conv outputs ----
    #pragma unroll
    for (int it = 0; it < 2; it++) {
        int idx = t + it * 256;          // 512 int4: row p = idx>>3, seg = idx&7
        int p = idx >> 3, seg = idx & 7;
        *(int4*)&xTg[(size_t)(bh * 64 + p) * SEQLEN + c * 64 + seg * 8] =
            *(const int4*)&sXT[p * 72 + seg * 8];
    }
    if (h == 0) {                        // bcg: 64 rows x 32 ch = 256 int4
        int s = t >> 2, seg = t & 3;
        *(int4*)&bcg[(size_t)(b * SEQLEN + c * 64 + s) * 32 + seg * 8] =
            *(const int4*)&sBC[s * 32 + seg * 8];
    }
}

// ---------- 5b. inter-chunk state scan: register-prefetched ----------
__global__ __launch_bounds__(1024)
void ssd_state_scan(float* __restrict__ hbuf, const float* __restrict__ pbuf) {
    int bh = blockIdx.x;
    int t = threadIdx.x;
    __shared__ float sP[NCHUNK];
    if (t < NCHUNK) sP[t] = pbuf[bh * NCHUNK + t];
    __syncthreads();
    size_t base = (size_t)bh * NCHUNK * 1024 + t;
    float v[NCHUNK];
    #pragma unroll
    for (int c = 0; c < NCHUNK; c++) v[c] = hbuf[base + (size_t)c * 1024];
    float carry = 0.f;
    #pragma unroll
    for (int c = 0; c < NCHUNK; c++) {
        float tmp = v[c];
        v[c] = carry;
        carry = tmp + sP[c] * carry;
    }
    #pragma unroll
    for (int c = 0; c < NCHUNK; c++) hbuf[base + (size_t)c * 1024] = v[c];
}

// ---------- 5c. y kernel (pure MFMA + epilogue): yq = fp8(YSCALE*(M.X + scale*(C.h_in))*silu(z)) ----------
// D*x folded into M's diagonal. z held in registers (loaded at kernel start,
// latency hidden under the MFMA body) -> LDS 40.5 -> 31.75 KB => 3 -> 5 blocks/CU.
__global__ __launch_bounds__(256)
void ssd_yfused(const unsigned short* __restrict__ zx,
                const unsigned short* __restrict__ xTg, const unsigned short* __restrict__ bcg,
                const float* __restrict__ scA,
                const float* __restrict__ A_log, const float* __restrict__ D_param,
                const float* __restrict__ hbuf,
                unsigned char* __restrict__ y, float* __restrict__ ssq) {
    __shared__ unsigned short sXT[64 * 72];
    __shared__ unsigned short sM[64 * 72];
    __shared__ unsigned short sB[64 * 32];
    __shared__ unsigned short sC[64 * 32];
    __shared__ unsigned short sHT[64 * 40];
    __shared__ float sdt[64], scd[64], sSc[64];

    const int blk = blockIdx.x;
    const int c  = blk & 31;
    const int h  = (blk >> 5) & 31;
    const int b  = blk >> 10;
    const int bh = blk >> 5;
    const int row0 = b * SEQLEN + c * QCHUNK;

    const int t    = threadIdx.x;
    const int w    = t >> 6;
    const int lane = t & 63;
    const int lm   = lane & 15;
    const int lq8  = (lane >> 4) * 8;
    const int lq4  = (lane >> 4) * 4;
    const float Ah = -__expf(A_log[h]);

    // ---- z -> registers (exact values the epilogue needs; coalesced per 16-lane group) ----
    unsigned short zreg[4][4];
    #pragma unroll
    for (int r = 0; r < 4; r++)
        #pragma unroll
        for (int pb = 0; pb < 4; pb++)
            zreg[r][pb] = zx[(size_t)(row0 + w * 16 + lq4 + r) * NPAD + h * 64 + pb * 16 + lm];

    // ---- staging (all vector loads) ----
    #pragma unroll
    for (int it = 0; it < 2; it++) {
        int idx = t + it * 256;          // X^T: 512 int4
        int p = idx >> 3, seg = idx & 7;
        *(int4*)&sXT[p * 72 + seg * 8] =
            *(const int4*)&xTg[(size_t)(bh * 64 + p) * SEQLEN + c * 64 + seg * 8];
    }
    {                                    // B/C: 256 int4
        int s = t >> 2, seg = t & 3;
        int4 v = *(const int4*)&bcg[(size_t)(b * SEQLEN + c * 64 + s) * 32 + seg * 8];
        if (seg < 2) *(int4*)&sB[s * 32 + seg * 8] = v;
        else         *(int4*)&sC[s * 32 + (seg - 2) * 8] = v;
    }
    {                                    // h_in -> sHT [p][n] bf16
        size_t hb = (size_t)(bh * NCHUNK + c) * 1024 + (size_t)t * 4;
        float4 hv = *(const float4*)&hbuf[hb];
        int n = t >> 4;
        int p0 = (t * 4) & 63;
        sHT[(p0 + 0) * 40 + n] = f2b(hv.x);
        sHT[(p0 + 1) * 40 + n] = f2b(hv.y);
        sHT[(p0 + 2) * 40 + n] = f2b(hv.z);
        sHT[(p0 + 3) * 40 + n] = f2b(hv.w);
    }
    if (t < 64) {                        // pads
        *(int4*)&sB[t * 32 + 16] = (int4){0, 0, 0, 0};
        *(int4*)&sB[t * 32 + 24] = (int4){0, 0, 0, 0};
        *(int4*)&sC[t * 32 + 16] = (int4){0, 0, 0, 0};
        *(int4*)&sC[t * 32 + 24] = (int4){0, 0, 0, 0};
        *(int4*)&sHT[t * 40 + 16] = (int4){0, 0, 0, 0};
        *(int4*)&sHT[t * 40 + 24] = (int4){0, 0, 0, 0};
    }
    if (t < 192) {                       // dt / cd / scale
        float v = scA[(size_t)(bh * NCHUNK + c) * 192 + t];
        if (t < 64) sdt[t] = v;
        else if (t < 128) scd[t - 64] = v;
        else sSc[t - 128] = v;
    }
    __syncthreads();

    // ---- S = C * B^T (lower-triangular blocks) ----
    f32x4 sacc[4];
    {
        bf16x8 cfrag = *(const bf16x8*)&sC[(w * 16 + lm) * 32 + lq8];
        #pragma unroll
        for (int sb = 0; sb < 4; sb++) {
            if (sb <= w) {
                bf16x8 bfrag = *(const bf16x8*)&sB[(sb * 16 + lm) * 32 + lq8];
                sacc[sb] = __builtin_amdgcn_mfma_f32_16x16x32_bf16(
                    cfrag, bfrag, (f32x4){0.f, 0.f, 0.f, 0.f}, 0, 0, 0);
            }
        }
    }
    // ---- M[t][s] with D on the diagonal ----
    const float Dh = D_param[h];
    #pragma unroll
    for (int sb = 0; sb < 4; sb++) {
        int sp = sb * 16 + lm;
        if (sb > w) {
            #pragma unroll
            for (int r = 0; r < 4; r++) sM[(w * 16 + lq4 + r) * 72 + sp] = 0;
        } else {
            float dts = sdt[sp], cds = scd[sp];
            #pragma unroll
            for (int r = 0; r < 4; r++) {
                int tp = w * 16 + lq4 + r;
                float m = 0.f;
                if (sb < w || sp <= tp) {
                    m = sacc[sb][r] * dts * __expf(Ah * (scd[tp] - cds));
                    if (sp == tp) m += Dh;
                }
                sM[tp * 72 + sp] = f2b(m);
            }
        }
    }

    // ---- Y1 = M * X ----
    f32x4 yacc[4];
    #pragma unroll
    for (int pb = 0; pb < 4; pb++) yacc[pb] = (f32x4){0.f, 0.f, 0.f, 0.f};
    #pragma unroll
    for (int ks = 0; ks < 2; ks++) {
        if (ks == 1 && w < 2) continue;
        bf16x8 af = *(const bf16x8*)&sM[(w * 16 + lm) * 72 + ks * 32 + lq8];
        #pragma unroll
        for (int pb = 0; pb < 4; pb++) {
            bf16x8 bf_ = *(const bf16x8*)&sXT[(pb * 16 + lm) * 72 + ks * 32 + lq8];
            yacc[pb] = __builtin_amdgcn_mfma_f32_16x16x32_bf16(af, bf_, yacc[pb], 0, 0, 0);
        }
    }
    // ---- Y2 = C * h_in^T ----
    f32x4 acc2[4];
    {
        bf16x8 cf2 = *(const bf16x8*)&sC[(w * 16 + lm) * 32 + lq8];
        #pragma unroll
        for (int pb = 0; pb < 4; pb++) {
            bf16x8 hf = *(const bf16x8*)&sHT[(pb * 16 + lm) * 40 + lq8];
            acc2[pb] = __builtin_amdgcn_mfma_f32_16x16x32_bf16(
                cf2, hf, (f32x4){0.f, 0.f, 0.f, 0.f}, 0, 0, 0);
        }
    }

    // ---- epilogue: z-gate, fp8 store, ssq partials ----
    #pragma unroll
    for (int r = 0; r < 4; r++) {
        const int tp = w * 16 + lq4 + r;
        const size_t yrow = (size_t)(row0 + tp) * D_INNER + h * 64;
        float ssr = 0.f;
        #pragma unroll
        for (int pb = 0; pb < 4; pb++) {
            int pp = pb * 16 + lm;
            float val = yacc[pb][r] + sSc[tp] * acc2[pb][r];
            float zv = b2f(zreg[r][pb]);
            float yg = val * (zv / (1.f + __expf(-zv)));
            ssr += yg * yg;
            y[yrow + pp] = f2fp8(yg * YSCALE);
        }
        ssr += __shfl_xor(ssr, 1, 16);
        ssr += __shfl_xor(ssr, 2, 16);
        ssr += __shfl_xor(ssr, 4, 16);
        ssr += __shfl_xor(ssr, 8, 16);
        if (lm == 0)
            ssq[(size_t)(row0 + tp) * NHEADS + h] = ssr;
    }
}

// ---------- launcher ----------
extern "C" void kernel_launch(void* const* d_in, const int* in_sizes, int n_in,
                              void* d_out, int out_size, void* d_ws, size_t ws_size,
                              hipStream_t stream) {
    const float* x        = (const float*)d_in[0];
    const float* W_in     = (const float*)d_in[1];
    const float* conv_w   = (const float*)d_in[2];
    const float* conv_b   = (const float*)d_in[3];
    const float* dt_bias  = (const float*)d_in[4];
    const float* A_log    = (const float*)d_in[5];
    const float* D_param  = (const float*)d_in[6];
    const float* norm_w   = (const float*)d_in[7];
    const float* W_out    = (const float*)d_in[8];
    const float* ls       = (const float*)d_in[9];
    float* out = (float*)d_out;

    char* ws = (char*)d_ws;
    size_t off = 0;
    unsigned char*  x_f8  = (unsigned char*)(ws + off);  off += (size_t)MROWS * D_MODEL;       // 8.4 MB
    unsigned char*  winT  = (unsigned char*)(ws + off);  off += (size_t)NPAD * D_MODEL;        // 4.3 MB
    unsigned char*  woutT = (unsigned char*)(ws + off);  off += (size_t)D_MODEL * D_INNER;     // 2.1 MB
    unsigned short* zx    = (unsigned short*)(ws + off); off += (size_t)MROWS * NPAD * 2;      // 69.2 MB
    float*          pbuf  = (float*)(ws + off);          off += (size_t)BATCH * NHEADS * NCHUNK * 4;
    unsigned char*  yb    = (unsigned char*)(ws + off);  off += (size_t)MROWS * D_INNER;       // 16.8 MB
    float*          ssq   = (float*)(ws + off);          off += (size_t)MROWS * NHEADS * 4;    // 1 MB
    float*          hbuf  = (float*)(ws + off);          off += (size_t)BATCH * NHEADS * NCHUNK * 1024 * 4; // 16.8 MB
    unsigned short* xTg   = (unsigned short*)(ws + off); off += (size_t)MROWS * D_INNER * 2;   // 33.5 MB
    unsigned short* bcg   = (unsigned short*)(ws + off); off += (size_t)MROWS * 32 * 2;        // 0.5 MB
    float*          scA   = (float*)(ws + off);          off += (size_t)BATCH * NHEADS * NCHUNK * 192 * 4; // 3.1 MB

    pre_kernel<<<8192 + 1568, 256, 0, stream>>>(x, x_f8, W_in, winT, W_out, woutT, norm_w);
    // in-proj: M=8192, N=4224, K=1024 -> 64 M-tiles x 33 N-tiles = 2112 blocks
    gemm_fp8<0, 4><<<(NPAD / 128) * 64, 256, 0, stream>>>(
        x_f8, winT, D_MODEL, NPAD, zx, nullptr, nullptr, nullptr, nullptr);
    ssd_hcomp<<<BATCH * NHEADS * NCHUNK, 256, 0, stream>>>(
        zx, dt_bias, conv_w, conv_b, A_log, hbuf, pbuf, xTg, bcg, scA);
    ssd_state_scan<<<BATCH * NHEADS, 1024, 0, stream>>>(hbuf, pbuf);
    ssd_yfused<<<BATCH * NHEADS * NCHUNK, 256, 0, stream>>>(
        zx, xTg, bcg, scA, A_log, D_param, hbuf, yb, ssq);
    // out-proj: M=8192, N=1024, K=2048, BN=64 -> 64 M-tiles x 16 N-tiles = 1024 blocks
    gemm_fp8<1, 2><<<(D_MODEL / 64) * 64, 256, 0, stream>>>(
        yb, woutT, D_INNER, D_MODEL, nullptr, out, x, ls, ssq);
}

// Round 6
// 268.137 us; speedup vs baseline: 1.0445x; 1.0053x over previous
//
#include <hip/hip_runtime.h>
#include <hip/hip_bf16.h>

// ---------- constants ----------
#define D_MODEL   1024
#define D_STATE   16
#define D_CONV    4
#define HEADDIM   64
#define NHEADS    32
#define D_INNER   2048
#define CONV_DIM  2080           // D_INNER + 2*D_STATE
#define D_IN_PROJ 4160           // 2*D_INNER + 2*D_STATE + NHEADS
#define NPAD      4224           // D_IN_PROJ padded to x128
#define BATCH     4
#define SEQLEN    2048
#define MROWS     (BATCH*SEQLEN) // 8192
#define QCHUNK    64
#define NCHUNK    (SEQLEN/QCHUNK) // 32
#define DT_COL    (2*D_INNER + 2*D_STATE)   // 4128: dt raw column in zx

// weight pre-scale (better e4m3 utilization); inverses folded into epilogues
#define WSCALE    16.f
#define YSCALE    64.f

// ---------- helpers ----------
__device__ __forceinline__ unsigned short f2b(float f) {
    union { float f; unsigned int u; } v; v.f = f;
    unsigned int r = (v.u + 0x7FFFu + ((v.u >> 16) & 1u)) >> 16;
    return (unsigned short)r;
}
__device__ __forceinline__ float b2f(unsigned short h) {
    union { unsigned int u; float f; } v; v.u = ((unsigned int)h) << 16;
    return v.f;
}
__device__ __forceinline__ unsigned char f2fp8(float f) {
    return (unsigned char)(__builtin_amdgcn_cvt_pk_fp8_f32(f, 0.f, 0, false) & 0xFF);
}

typedef __attribute__((ext_vector_type(8))) short bf16x8;
typedef __attribute__((ext_vector_type(4))) float f32x4;
typedef __attribute__((ext_vector_type(4))) int   i32x4;
typedef __attribute__((ext_vector_type(8))) int   i32x8;

__device__ __forceinline__ i32x8 cat8(i32x4 a, i32x4 b) {
    i32x8 r;
    r[0] = a[0]; r[1] = a[1]; r[2] = a[2]; r[3] = a[3];
    r[4] = b[0]; r[5] = b[1]; r[6] = b[2]; r[7] = b[3];
    return r;
}

__device__ __forceinline__ void async_copy16b(const unsigned char* g, unsigned char* l) {
    __builtin_amdgcn_global_load_lds(
        (const __attribute__((address_space(1))) void*)g,
        (__attribute__((address_space(3))) void*)l, 16, 0, 0);
}

// ---------- 1+2 fused: cast fp32->fp8 AND both weight transposes ----------
__global__ __launch_bounds__(256)
void pre_kernel(const float* __restrict__ x, unsigned char* __restrict__ x_f8,
                const float* __restrict__ W_in, unsigned char* __restrict__ winT,
                const float* __restrict__ W_out, unsigned char* __restrict__ woutT,
                const float* __restrict__ norm_w) {
    __shared__ float tile[64][65];
    int bid = blockIdx.x;
    if (bid < 8192) {                    // cast path: 8192 blocks x 1024 elems
        int i = (bid * 256 + threadIdx.x) * 4;
        float4 v = *(const float4*)&x[i];
        int p = __builtin_amdgcn_cvt_pk_fp8_f32(v.x, v.y, 0, false);
        p = __builtin_amdgcn_cvt_pk_fp8_f32(v.z, v.w, p, true);
        *(unsigned int*)&x_f8[i] = (unsigned int)p;
        return;
    }
    bid -= 8192;                         // transpose path: 1568 blocks
    const float* W; unsigned char* WT; const float* kscale;
    int K, N, bx, by;
    if (bid < 1056) { W = W_in;  WT = winT;  kscale = nullptr; K = 1024; N = 4160; bx = bid % 66; by = bid / 66; }
    else { bid -= 1056; W = W_out; WT = woutT; kscale = norm_w; K = 2048; N = 1024; bx = bid % 16; by = bid / 16; }
    int n0 = bx * 64, k0 = by * 64;
    int tx = threadIdx.x & 63, ty = threadIdx.x >> 6;
    #pragma unroll
    for (int i = 0; i < 16; i++) {
        int r = ty * 16 + i;
        int n = n0 + tx;
        float v = (n < N) ? W[(size_t)(k0 + r) * N + n] : 0.f;
        tile[r][tx] = v;
    }
    __syncthreads();
    float ks = WSCALE * (kscale ? kscale[k0 + tx] : 1.f);
    #pragma unroll
    for (int i = 0; i < 16; i++) {
        int r = ty * 16 + i;
        WT[(size_t)(n0 + r) * K + k0 + tx] = f2fp8(tile[tx][r] * ks);
    }
}

// ---------- 3. fp8 MFMA GEMM (MX-scaled K=128), BMx(NF*32) tile ----------
// EXACT baseline structure (single-buffered, global_load_lds, serial K-loop,
// per-XCD-pinned A panels): r1/r3/r4 proved every ILP scheme here loses to
// multi-block TLP. NF=4 -> 128x128 (in-proj); NF=2 -> 128x64 (out-proj,
// 1024 blocks = 4/CU). EPI==1 fuses the per-row rsqrt into the epilogue.
template <int EPI, int NF>
__global__ __launch_bounds__(256)
void gemm_fp8(const unsigned char* __restrict__ A, const unsigned char* __restrict__ B,
              int K, int N, unsigned short* __restrict__ Cb,
              float* __restrict__ Cf, const float* __restrict__ xres,
              const float* __restrict__ ls, const float* __restrict__ ssq) {
    constexpr int BN = NF * 32;
    __shared__ unsigned char lds_a[128 * 128];
    __shared__ unsigned char lds_b[BN * 128];
    const int tid  = threadIdx.x;
    const int wave = tid >> 6;
    const int lane = tid & 63;
    const int bid = blockIdx.x;
    const int xcd = bid & 7, g = bid >> 3;
    const int bm = xcd * 8 + (g & 7);    // 8 A-panels pinned per XCD
    const int bn = g >> 3;
    const int wm = wave >> 1, wn = wave & 1;

    f32x4 acc[4][NF];
    #pragma unroll
    for (int i = 0; i < 4; i++)
        #pragma unroll
        for (int j = 0; j < NF; j++) acc[i][j] = (f32x4){0.f, 0.f, 0.f, 0.f};

    const int srow = lane >> 3;
    const int sseg = (lane & 7) ^ srow;
    const unsigned char* gA0 = A + (size_t)(bm * 128 + wave * 8 + srow) * K + sseg * 16;
    const unsigned char* gB0 = B + (size_t)(bn * BN  + wave * 8 + srow) * K + sseg * 16;
    const int ldsbase = wave * 8 * 128;

    const int lm = lane & 15, q = lane >> 4;

    for (int k0 = 0; k0 < K; k0 += 128) {
        #pragma unroll
        for (int j = 0; j < 4; j++)
            async_copy16b(gA0 + k0 + (size_t)(j * 32) * K, &lds_a[ldsbase + j * 32 * 128]);
        #pragma unroll
        for (int j = 0; j < NF; j++)
            async_copy16b(gB0 + k0 + (size_t)(j * 32) * K, &lds_b[ldsbase + j * 32 * 128]);
        __syncthreads();

        i32x8 af[4], bfr[NF];
        #pragma unroll
        for (int i = 0; i < 4; i++) {
            int r = wm * 64 + i * 16 + lm;
            int s0 = ((2 * q) ^ (r & 7)) * 16, s1 = ((2 * q + 1) ^ (r & 7)) * 16;
            af[i] = cat8(*(const i32x4*)&lds_a[r * 128 + s0],
                         *(const i32x4*)&lds_a[r * 128 + s1]);
        }
        #pragma unroll
        for (int j = 0; j < NF; j++) {
            int r = wn * (NF * 16) + j * 16 + lm;
            int s0 = ((2 * q) ^ (r & 7)) * 16, s1 = ((2 * q + 1) ^ (r & 7)) * 16;
            bfr[j] = cat8(*(const i32x4*)&lds_b[r * 128 + s0],
                          *(const i32x4*)&lds_b[r * 128 + s1]);
        }
        #pragma unroll
        for (int i = 0; i < 4; i++)
            #pragma unroll
            for (int j = 0; j < NF; j++)
                acc[i][j] = __builtin_amdgcn_mfma_scale_f32_16x16x128_f8f6f4(
                    af[i], bfr[j], acc[i][j], 0, 0,
                    0, 0x7F7F7F7F, 0, 0x7F7F7F7F);
        __syncthreads();
    }

    // fused per-row rsqrt scale, LDS reused after K-loop
    float* srs = (float*)lds_a;
    if constexpr (EPI == 1) {
        if (tid < 128) {
            const float4* p = (const float4*)&ssq[(size_t)(bm * 128 + tid) * NHEADS];
            float s = 0.f;
            #pragma unroll
            for (int i2 = 0; i2 < 8; i2++) {
                float4 v4 = p[i2];
                s += v4.x + v4.y + v4.z + v4.w;
            }
            srs[tid] = rsqrtf(s * (1.f / D_INNER) + 1e-5f);
        }
        __syncthreads();
    }

    const int row0 = bm * 128 + wm * 64;
    const int col0 = bn * BN + wn * (NF * 16);
    const int lq = (lane >> 4) * 4;
    #pragma unroll
    for (int i = 0; i < 4; i++) {
        #pragma unroll
        for (int j = 0; j < NF; j++) {
            #pragma unroll
            for (int r = 0; r < 4; r++) {
                int gr = row0 + i * 16 + lq + r;
                int gc = col0 + j * 16 + lm;
                float v = acc[i][j][r];
                if constexpr (EPI == 0) {
                    Cb[(size_t)gr * N + gc] = f2b(v * (1.f / WSCALE));
                } else {
                    size_t idx = (size_t)gr * 1024 + gc;
                    float rsv = srs[wm * 64 + i * 16 + lq + r];
                    Cf[idx] = xres[idx] + v * ls[gc] * rsv * (1.f / (WSCALE * YSCALE));
                }
            }
        }
    }
}

// ---------- 5a. conv + chunk-local state; persists conv(B/C), h_local(bf16), dt/cd/scale ----------
// (xTg persist removed: yfused recomputes conv(X) locally — saves 67 MB of HBM round-trip)
__global__ __launch_bounds__(256)
void ssd_hcomp(const unsigned short* __restrict__ zx, const float* __restrict__ dt_bias,
               const float* __restrict__ conv_w, const float* __restrict__ conv_b,
               const float* __restrict__ A_log,
               unsigned short* __restrict__ hbuf, float* __restrict__ pbuf,
               unsigned short* __restrict__ bcg, float* __restrict__ scA) {
    __shared__ unsigned short sXraw[67 * 64];
    __shared__ unsigned short sBCraw[67 * 32];
    __shared__ unsigned short sXT[64 * 72];
    __shared__ unsigned short sBC[64 * 32];
    __shared__ unsigned short sBwT[16 * 72];
    __shared__ float sdt[64], scd[64];

    const int blk = blockIdx.x;
    const int c  = blk & 31;
    const int h  = (blk >> 5) & 31;
    const int b  = blk >> 10;
    const int bh = blk >> 5;
    const int row0 = b * SEQLEN + c * QCHUNK;
    const int batch0 = b * SEQLEN;

    const int t    = threadIdx.x;
    const int w    = t >> 6;
    const int lane = t & 63;
    const int lm   = lane & 15;
    const int lq8  = (lane >> 4) * 8;
    const int lq4  = (lane >> 4) * 4;
    const float Ah = -__expf(A_log[h]);

    // ---- phase 1: halo staging + dt softplus/prefix ----
    for (int i = t; i < 536; i += 256) {
        int r = i >> 3, seg = i & 7;
        int gr = row0 - 3 + r;
        int4 v = (gr >= batch0) ? *(const int4*)&zx[(size_t)gr * NPAD + D_INNER + h * 64 + seg * 8]
                                : (int4){0, 0, 0, 0};
        *(int4*)&sXraw[r * 64 + seg * 8] = v;
    }
    for (int i = t; i < 268; i += 256) {
        int r = i >> 2, seg = i & 3;
        int gr = row0 - 3 + r;
        int4 v = (gr >= batch0) ? *(const int4*)&zx[(size_t)gr * NPAD + 2 * D_INNER + seg * 8]
                                : (int4){0, 0, 0, 0};
        *(int4*)&sBCraw[r * 32 + seg * 8] = v;
    }
    if (t < 64) {
        float raw = b2f(zx[(size_t)(row0 + t) * NPAD + DT_COL + h]) + dt_bias[h];
        float dtv = (raw > 20.f) ? raw : log1pf(__expf(raw));
        float v = dtv;
        #pragma unroll
        for (int o = 1; o < 64; o <<= 1) {
            float u = __shfl_up(v, o, 64);
            if (t >= o) v += u;
        }
        sdt[t] = dtv;
        scd[t] = v;
        float sc = __expf(Ah * v);
        float* scrow = &scA[(size_t)(bh * NCHUNK + c) * 192];
        scrow[t] = dtv; scrow[64 + t] = v; scrow[128 + t] = sc;
        if (t == 63) pbuf[bh * NCHUNK + c] = sc;
    }
    __syncthreads();

    // ---- phase 2: conv + silu (sliding window) ----
    {   // X: thread owns column p, 16 s values
        const int p = t & 63, sblk = (t >> 6) * 16;
        const int ch = h * 64 + p;
        const float4 cw = *(const float4*)&conv_w[ch * 4];
        const float cb = conv_b[ch];
        float x0 = b2f(sXraw[(sblk + 0) * 64 + p]);
        float x1 = b2f(sXraw[(sblk + 1) * 64 + p]);
        float x2 = b2f(sXraw[(sblk + 2) * 64 + p]);
        #pragma unroll
        for (int i = 0; i < 16; i++) {
            float x3 = b2f(sXraw[(sblk + i + 3) * 64 + p]);
            float acc = cb + cw.x * x0 + cw.y * x1 + cw.z * x2 + cw.w * x3;
            float sv = acc / (1.f + __expf(-acc));
            sXT[p * 72 + sblk + i] = f2b(sv);
            x0 = x1; x1 = x2; x2 = x3;
        }
    }
    {   // B/C: thread owns channel ch32, 8 s values; ch32<16 also writes weighted Bw^T
        const int ch32 = t & 31, s0 = (t >> 5) * 8;
        const int ch = D_INNER + ch32;
        const float4 cw = *(const float4*)&conv_w[ch * 4];
        const float cb = conv_b[ch];
        const float cdl = scd[63];
        float x0 = b2f(sBCraw[(s0 + 0) * 32 + ch32]);
        float x1 = b2f(sBCraw[(s0 + 1) * 32 + ch32]);
        float x2 = b2f(sBCraw[(s0 + 2) * 32 + ch32]);
        #pragma unroll
        for (int i = 0; i < 8; i++) {
            int s = s0 + i;
            float x3 = b2f(sBCraw[(s + 3) * 32 + ch32]);
            float acc = cb + cw.x * x0 + cw.y * x1 + cw.z * x2 + cw.w * x3;
            float sv = acc / (1.f + __expf(-acc));
            sBC[s * 32 + ch32] = f2b(sv);
            if (ch32 < 16) {
                float wgt = sdt[s] * __expf(Ah * (cdl - scd[s]));
                sBwT[ch32 * 72 + s] = f2b(sv * wgt);
            }
            x0 = x1; x1 = x2; x2 = x3;
        }
    }
    __syncthreads();

    // ---- phase 3: h_local = Bw^T X  (stored bf16: consumer converts anyway) ----
    f32x4 hacc = (f32x4){0.f, 0.f, 0.f, 0.f};
    #pragma unroll
    for (int ks = 0; ks < 2; ks++) {
        bf16x8 af = *(const bf16x8*)&sBwT[lm * 72 + ks * 32 + lq8];
        bf16x8 bf_ = *(const bf16x8*)&sXT[(w * 16 + lm) * 72 + ks * 32 + lq8];
        hacc = __builtin_amdgcn_mfma_f32_16x16x32_bf16(af, bf_, hacc, 0, 0, 0);
    }
    #pragma unroll
    for (int r = 0; r < 4; r++)
        hbuf[(size_t)(bh * NCHUNK + c) * 1024 + (lq4 + r) * 64 + (w * 16 + lm)] = f2b(hacc[r]);

    if (h == 0) {                        // bcg: 64 rows x 32 ch = 256 int4
        int s = t >> 2, seg = t & 3;
        *(int4*)&bcg[(size_t)(b * SEQLEN + c * 64 + s) * 32 + seg * 8] =
            *(const int4*)&sBC[s * 32 + seg * 8];
    }
}

// ---------- 5b. inter-chunk state scan (bf16 storage, f32 recurrence) ----------
__global__ __launch_bounds__(1024)
void ssd_state_scan(unsigned short* __restrict__ hbuf, const float* __restrict__ pbuf) {
    int bh = blockIdx.x;
    int t = threadIdx.x;
    __shared__ float sP[NCHUNK];
    if (t < NCHUNK) sP[t] = pbuf[bh * NCHUNK + t];
    __syncthreads();
    size_t base = (size_t)bh * NCHUNK * 1024 + t;
    float v[NCHUNK];
    #pragma unroll
    for (int c = 0; c < NCHUNK; c++) v[c] = b2f(hbuf[base + (size_t)c * 1024]);
    float carry = 0.f;
    #pragma unroll
    for (int c = 0; c < NCHUNK; c++) {
        float tmp = v[c];
        v[c] = carry;
        carry = tmp + sP[c] * carry;
    }
    #pragma unroll
    for (int c = 0; c < NCHUNK; c++) hbuf[base + (size_t)c * 1024] = f2b(v[c]);
}

// ---------- 5c. y kernel: recomputes conv(X)+silu locally (no xTg), bf16 h_in ----------
// yq = fp8(YSCALE*(M.X + scale*(C.h_in))*silu(z)); D*x folded into M's diagonal.
// sXraw (conv staging, dead after conv) aliases sM (written after conv) -> no LDS growth.
__global__ __launch_bounds__(256)
void ssd_yfused(const unsigned short* __restrict__ zx,
                const float* __restrict__ conv_w, const float* __restrict__ conv_b,
                const unsigned short* __restrict__ bcg,
                const float* __restrict__ scA,
                const float* __restrict__ A_log, const float* __restrict__ D_param,
                const unsigned short* __restrict__ hbuf,
                unsigned char* __restrict__ y, float* __restrict__ ssq) {
    __shared__ unsigned short sXT[64 * 72];
    __shared__ unsigned short sMX[64 * 72];   // first sXraw[67*64] (8576B), then sM[64*72]
    __shared__ unsigned short sB[64 * 32];
    __shared__ unsigned short sC[64 * 32];
    __shared__ unsigned short sHT[64 * 40];
    __shared__ float sdt[64], scd[64], sSc[64];
    unsigned short* sXraw = sMX;
    unsigned short* sM    = sMX;

    const int blk = blockIdx.x;
    const int c  = blk & 31;
    const int h  = (blk >> 5) & 31;
    const int b  = blk >> 10;
    const int bh = blk >> 5;
    const int row0 = b * SEQLEN + c * QCHUNK;
    const int batch0 = b * SEQLEN;

    const int t    = threadIdx.x;
    const int w    = t >> 6;
    const int lane = t & 63;
    const int lm   = lane & 15;
    const int lq8  = (lane >> 4) * 8;
    const int lq4  = (lane >> 4) * 4;
    const float Ah = -__expf(A_log[h]);

    // ---- z -> registers (exact values the epilogue needs) ----
    unsigned short zreg[4][4];
    #pragma unroll
    for (int r = 0; r < 4; r++)
        #pragma unroll
        for (int pb = 0; pb < 4; pb++)
            zreg[r][pb] = zx[(size_t)(row0 + w * 16 + lq4 + r) * NPAD + h * 64 + pb * 16 + lm];

    // ---- staging ----
    for (int i = t; i < 536; i += 256) {  // X raw (with 3-row halo) for conv recompute
        int r = i >> 3, seg = i & 7;
        int gr = row0 - 3 + r;
        int4 v = (gr >= batch0) ? *(const int4*)&zx[(size_t)gr * NPAD + D_INNER + h * 64 + seg * 8]
                                : (int4){0, 0, 0, 0};
        *(int4*)&sXraw[r * 64 + seg * 8] = v;
    }
    {                                    // B/C: 256 int4
        int s = t >> 2, seg = t & 3;
        int4 v = *(const int4*)&bcg[(size_t)(b * SEQLEN + c * 64 + s) * 32 + seg * 8];
        if (seg < 2) *(int4*)&sB[s * 32 + seg * 8] = v;
        else         *(int4*)&sC[s * 32 + (seg - 2) * 8] = v;
    }
    {                                    // h_in (bf16) -> sHT [p][n]
        size_t hb = (size_t)(bh * NCHUNK + c) * 1024 + (size_t)t * 4;
        const unsigned short* hp = &hbuf[hb];
        int n = t >> 4;
        int p0 = (t * 4) & 63;
        sHT[(p0 + 0) * 40 + n] = hp[0];
        sHT[(p0 + 1) * 40 + n] = hp[1];
        sHT[(p0 + 2) * 40 + n] = hp[2];
        sHT[(p0 + 3) * 40 + n] = hp[3];
    }
    if (t < 64) {                        // pads
        *(int4*)&sB[t * 32 + 16] = (int4){0, 0, 0, 0};
        *(int4*)&sB[t * 32 + 24] = (int4){0, 0, 0, 0};
        *(int4*)&sC[t * 32 + 16] = (int4){0, 0, 0, 0};
        *(int4*)&sC[t * 32 + 24] = (int4){0, 0, 0, 0};
        *(int4*)&sHT[t * 40 + 16] = (int4){0, 0, 0, 0};
        *(int4*)&sHT[t * 40 + 24] = (int4){0, 0, 0, 0};
    }
    if (t < 192) {                       // dt / cd / scale
        float v = scA[(size_t)(bh * NCHUNK + c) * 192 + t];
        if (t < 64) sdt[t] = v;
        else if (t < 128) scd[t - 64] = v;
        else sSc[t - 128] = v;
    }
    __syncthreads();

    // ---- S = C * B^T (lower-triangular blocks) ----
    f32x4 sacc[4];
    {
        bf16x8 cfrag = *(const bf16x8*)&sC[(w * 16 + lm) * 32 + lq8];
        #pragma unroll
        for (int sb = 0; sb < 4; sb++) {
            if (sb <= w) {
                bf16x8 bfrag = *(const bf16x8*)&sB[(sb * 16 + lm) * 32 + lq8];
                sacc[sb] = __builtin_amdgcn_mfma_f32_16x16x32_bf16(
                    cfrag, bfrag, (f32x4){0.f, 0.f, 0.f, 0.f}, 0, 0, 0);
            }
        }
    }
    // ---- conv + silu recompute: sXraw -> sXT (bit-identical to hcomp's) ----
    {
        const int p = t & 63, sblk = (t >> 6) * 16;
        const int ch = h * 64 + p;
        const float4 cw = *(const float4*)&conv_w[ch * 4];
        const float cb = conv_b[ch];
        float x0 = b2f(sXraw[(sblk + 0) * 64 + p]);
        float x1 = b2f(sXraw[(sblk + 1) * 64 + p]);
        float x2 = b2f(sXraw[(sblk + 2) * 64 + p]);
        #pragma unroll
        for (int i = 0; i < 16; i++) {
            float x3 = b2f(sXraw[(sblk + i + 3) * 64 + p]);
            float acc = cb + cw.x * x0 + cw.y * x1 + cw.z * x2 + cw.w * x3;
            float sv = acc / (1.f + __expf(-acc));
            sXT[p * 72 + sblk + i] = f2b(sv);
            x0 = x1; x1 = x2; x2 = x3;
        }
    }
    __syncthreads();   // sXraw reads done (sM may now overwrite); sXT visible to all

    // ---- M[t][s] with D on the diagonal (sM aliases dead sXraw) ----
    const float Dh = D_param[h];
    #pragma unroll
    for (int sb = 0; sb < 4; sb++) {
        int sp = sb * 16 + lm;
        if (sb > w) {
            #pragma unroll
            for (int r = 0; r < 4; r++) sM[(w * 16 + lq4 + r) * 72 + sp] = 0;
        } else {
            float dts = sdt[sp], cds = scd[sp];
            #pragma unroll
            for (int r = 0; r < 4; r++) {
                int tp = w * 16 + lq4 + r;
                float m = 0.f;
                if (sb < w || sp <= tp) {
                    m = sacc[sb][r] * dts * __expf(Ah * (scd[tp] - cds));
                    if (sp == tp) m += Dh;
                }
                sM[tp * 72 + sp] = f2b(m);
            }
        }
    }

    // ---- Y1 = M * X ----
    f32x4 yacc[4];
    #pragma unroll
    for (int pb = 0; pb < 4; pb++) yacc[pb] = (f32x4){0.f, 0.f, 0.f, 0.f};
    #pragma unroll
    for (int ks = 0; ks < 2; ks++) {
        if (ks == 1 && w < 2) continue;
        bf16x8 af = *(const bf16x8*)&sM[(w * 16 + lm) * 72 + ks * 32 + lq8];
        #pragma unroll
        for (int pb = 0; pb < 4; pb++) {
            bf16x8 bf_ = *(const bf16x8*)&sXT[(pb * 16 + lm) * 72 + ks * 32 + lq8];
            yacc[pb] = __builtin_amdgcn_mfma_f32_16x16x32_bf16(af, bf_, yacc[pb], 0, 0, 0);
        }
    }
    // ---- Y2 = C * h_in^T ----
    f32x4 acc2[4];
    {
        bf16x8 cf2 = *(const bf16x8*)&sC[(w * 16 + lm) * 32 + lq8];
        #pragma unroll
        for (int pb = 0; pb < 4; pb++) {
            bf16x8 hf = *(const bf16x8*)&sHT[(pb * 16 + lm) * 40 + lq8];
            acc2[pb] = __builtin_amdgcn_mfma_f32_16x16x32_bf16(
                cf2, hf, (f32x4){0.f, 0.f, 0.f, 0.f}, 0, 0, 0);
        }
    }

    // ---- epilogue: z-gate, fp8 store, ssq partials ----
    #pragma unroll
    for (int r = 0; r < 4; r++) {
        const int tp = w * 16 + lq4 + r;
        const size_t yrow = (size_t)(row0 + tp) * D_INNER + h * 64;
        float ssr = 0.f;
        #pragma unroll
        for (int pb = 0; pb < 4; pb++) {
            int pp = pb * 16 + lm;
            float val = yacc[pb][r] + sSc[tp] * acc2[pb][r];
            float zv = b2f(zreg[r][pb]);
            float yg = val * (zv / (1.f + __expf(-zv)));
            ssr += yg * yg;
            y[yrow + pp] = f2fp8(yg * YSCALE);
        }
        ssr += __shfl_xor(ssr, 1, 16);
        ssr += __shfl_xor(ssr, 2, 16);
        ssr += __shfl_xor(ssr, 4, 16);
        ssr += __shfl_xor(ssr, 8, 16);
        if (lm == 0)
            ssq[(size_t)(row0 + tp) * NHEADS + h] = ssr;
    }
}

// ---------- launcher ----------
extern "C" void kernel_launch(void* const* d_in, const int* in_sizes, int n_in,
                              void* d_out, int out_size, void* d_ws, size_t ws_size,
                              hipStream_t stream) {
    const float* x        = (const float*)d_in[0];
    const float* W_in     = (const float*)d_in[1];
    const float* conv_w   = (const float*)d_in[2];
    const float* conv_b   = (const float*)d_in[3];
    const float* dt_bias  = (const float*)d_in[4];
    const float* A_log    = (const float*)d_in[5];
    const float* D_param  = (const float*)d_in[6];
    const float* norm_w   = (const float*)d_in[7];
    const float* W_out    = (const float*)d_in[8];
    const float* ls       = (const float*)d_in[9];
    float* out = (float*)d_out;

    char* ws = (char*)d_ws;
    size_t off = 0;
    unsigned char*  x_f8  = (unsigned char*)(ws + off);  off += (size_t)MROWS * D_MODEL;       // 8.4 MB
    unsigned char*  winT  = (unsigned char*)(ws + off);  off += (size_t)NPAD * D_MODEL;        // 4.3 MB
    unsigned char*  woutT = (unsigned char*)(ws + off);  off += (size_t)D_MODEL * D_INNER;     // 2.1 MB
    unsigned short* zx    = (unsigned short*)(ws + off); off += (size_t)MROWS * NPAD * 2;      // 69.2 MB
    float*          pbuf  = (float*)(ws + off);          off += (size_t)BATCH * NHEADS * NCHUNK * 4;
    unsigned char*  yb    = (unsigned char*)(ws + off);  off += (size_t)MROWS * D_INNER;       // 16.8 MB
    float*          ssq   = (float*)(ws + off);          off += (size_t)MROWS * NHEADS * 4;    // 1 MB
    unsigned short* hbuf  = (unsigned short*)(ws + off); off += (size_t)BATCH * NHEADS * NCHUNK * 1024 * 2; // 8.4 MB
    unsigned short* bcg   = (unsigned short*)(ws + off); off += (size_t)MROWS * 32 * 2;        // 0.5 MB
    float*          scA   = (float*)(ws + off);          off += (size_t)BATCH * NHEADS * NCHUNK * 192 * 4; // 3.1 MB

    pre_kernel<<<8192 + 1568, 256, 0, stream>>>(x, x_f8, W_in, winT, W_out, woutT, norm_w);
    // in-proj: M=8192, N=4224, K=1024 -> 64 M-tiles x 33 N-tiles = 2112 blocks
    gemm_fp8<0, 4><<<(NPAD / 128) * 64, 256, 0, stream>>>(
        x_f8, winT, D_MODEL, NPAD, zx, nullptr, nullptr, nullptr, nullptr);
    ssd_hcomp<<<BATCH * NHEADS * NCHUNK, 256, 0, stream>>>(
        zx, dt_bias, conv_w, conv_b, A_log, hbuf, pbuf, bcg, scA);
    ssd_state_scan<<<BATCH * NHEADS, 1024, 0, stream>>>(hbuf, pbuf);
    ssd_yfused<<<BATCH * NHEADS * NCHUNK, 256, 0, stream>>>(
        zx, conv_w, conv_b, bcg, scA, A_log, D_param, hbuf, yb, ssq);
    // out-proj: M=8192, N=1024, K=2048, BN=64 -> 64 M-tiles x 16 N-tiles = 1024 blocks
    gemm_fp8<1, 2><<<(D_MODEL / 64) * 64, 256, 0, stream>>>(
        yb, woutT, D_INNER, D_MODEL, nullptr, out, x, ls, ssq);
}

// Round 7
// 256.147 us; speedup vs baseline: 1.0934x; 1.0468x over previous
//
#include <hip/hip_runtime.h>
#include <hip/hip_bf16.h>

// ---------- constants ----------
#define D_MODEL   1024
#define D_STATE   16
#define D_CONV    4
#define HEADDIM   64
#define NHEADS    32
#define D_INNER   2048
#define CONV_DIM  2080           // D_INNER + 2*D_STATE
#define D_IN_PROJ 4160           // 2*D_INNER + 2*D_STATE + NHEADS
#define NPAD      4224           // D_IN_PROJ padded to x128
#define BATCH     4
#define SEQLEN    2048
#define MROWS     (BATCH*SEQLEN) // 8192
#define QCHUNK    64
#define NCHUNK    (SEQLEN/QCHUNK) // 32
#define DT_COL    (2*D_INNER + 2*D_STATE)   // 4128: dt raw column in zx

// weight pre-scale (better e4m3 utilization); inverses folded into epilogues
#define WSCALE    16.f
#define YSCALE    64.f

// ---------- helpers ----------
__device__ __forceinline__ unsigned short f2b(float f) {
    union { float f; unsigned int u; } v; v.f = f;
    unsigned int r = (v.u + 0x7FFFu + ((v.u >> 16) & 1u)) >> 16;
    return (unsigned short)r;
}
__device__ __forceinline__ float b2f(unsigned short h) {
    union { unsigned int u; float f; } v; v.u = ((unsigned int)h) << 16;
    return v.f;
}
__device__ __forceinline__ unsigned char f2fp8(float f) {
    return (unsigned char)(__builtin_amdgcn_cvt_pk_fp8_f32(f, 0.f, 0, false) & 0xFF);
}

typedef __attribute__((ext_vector_type(8))) short bf16x8;
typedef __attribute__((ext_vector_type(4))) float f32x4;
typedef __attribute__((ext_vector_type(4))) int   i32x4;
typedef __attribute__((ext_vector_type(8))) int   i32x8;

__device__ __forceinline__ i32x8 cat8(i32x4 a, i32x4 b) {
    i32x8 r;
    r[0] = a[0]; r[1] = a[1]; r[2] = a[2]; r[3] = a[3];
    r[4] = b[0]; r[5] = b[1]; r[6] = b[2]; r[7] = b[3];
    return r;
}

__device__ __forceinline__ void async_copy16b(const unsigned char* g, unsigned char* l) {
    __builtin_amdgcn_global_load_lds(
        (const __attribute__((address_space(1))) void*)g,
        (__attribute__((address_space(3))) void*)l, 16, 0, 0);
}

// ---------- 1+2 fused: cast fp32->fp8 AND both weight transposes ----------
__global__ __launch_bounds__(256)
void pre_kernel(const float* __restrict__ x, unsigned char* __restrict__ x_f8,
                const float* __restrict__ W_in, unsigned char* __restrict__ winT,
                const float* __restrict__ W_out, unsigned char* __restrict__ woutT,
                const float* __restrict__ norm_w) {
    __shared__ float tile[64][65];
    int bid = blockIdx.x;
    if (bid < 8192) {                    // cast path: 8192 blocks x 1024 elems
        int i = (bid * 256 + threadIdx.x) * 4;
        float4 v = *(const float4*)&x[i];
        int p = __builtin_amdgcn_cvt_pk_fp8_f32(v.x, v.y, 0, false);
        p = __builtin_amdgcn_cvt_pk_fp8_f32(v.z, v.w, p, true);
        *(unsigned int*)&x_f8[i] = (unsigned int)p;
        return;
    }
    bid -= 8192;                         // transpose path: 1568 blocks
    const float* W; unsigned char* WT; const float* kscale;
    int K, N, bx, by;
    if (bid < 1056) { W = W_in;  WT = winT;  kscale = nullptr; K = 1024; N = 4160; bx = bid % 66; by = bid / 66; }
    else { bid -= 1056; W = W_out; WT = woutT; kscale = norm_w; K = 2048; N = 1024; bx = bid % 16; by = bid / 16; }
    int n0 = bx * 64, k0 = by * 64;
    int tx = threadIdx.x & 63, ty = threadIdx.x >> 6;
    #pragma unroll
    for (int i = 0; i < 16; i++) {
        int r = ty * 16 + i;
        int n = n0 + tx;
        float v = (n < N) ? W[(size_t)(k0 + r) * N + n] : 0.f;
        tile[r][tx] = v;
    }
    __syncthreads();
    float ks = WSCALE * (kscale ? kscale[k0 + tx] : 1.f);
    #pragma unroll
    for (int i = 0; i < 16; i++) {
        int r = ty * 16 + i;
        WT[(size_t)(n0 + r) * K + k0 + tx] = f2fp8(tile[tx][r] * ks);
    }
}

// ---------- 3. fp8 MFMA GEMM (MX-scaled K=128), BMx(NF*32) tile ----------
// Serial K-loop structure (r1/r3/r4 bracketed all pipelining variants as losses).
// r6 diagnosis: 72 VGPR + 64 AGPR acc = 136 regs/wave (unified file) -> only
// 2-3 waves/SIMD, matching measured 23% occupancy. Fix: A-fragments loaded
// one-at-a-time (live fragments 64->40 regs) + __launch_bounds__(256,4) to
// force total <=128 regs/wave -> 4 blocks/CU. MFMA sequence bit-identical.
template <int EPI, int NF>
__global__ __launch_bounds__(256, 4)
void gemm_fp8(const unsigned char* __restrict__ A, const unsigned char* __restrict__ B,
              int K, int N, unsigned short* __restrict__ Cb,
              float* __restrict__ Cf, const float* __restrict__ xres,
              const float* __restrict__ ls, const float* __restrict__ ssq) {
    constexpr int BN = NF * 32;
    __shared__ unsigned char lds_a[128 * 128];
    __shared__ unsigned char lds_b[BN * 128];
    const int tid  = threadIdx.x;
    const int wave = tid >> 6;
    const int lane = tid & 63;
    const int bid = blockIdx.x;
    const int xcd = bid & 7, g = bid >> 3;
    const int bm = xcd * 8 + (g & 7);    // 8 A-panels pinned per XCD
    const int bn = g >> 3;
    const int wm = wave >> 1, wn = wave & 1;

    f32x4 acc[4][NF];
    #pragma unroll
    for (int i = 0; i < 4; i++)
        #pragma unroll
        for (int j = 0; j < NF; j++) acc[i][j] = (f32x4){0.f, 0.f, 0.f, 0.f};

    const int srow = lane >> 3;
    const int sseg = (lane & 7) ^ srow;
    const unsigned char* gA0 = A + (size_t)(bm * 128 + wave * 8 + srow) * K + sseg * 16;
    const unsigned char* gB0 = B + (size_t)(bn * BN  + wave * 8 + srow) * K + sseg * 16;
    const int ldsbase = wave * 8 * 128;

    const int lm = lane & 15, q = lane >> 4;

    for (int k0 = 0; k0 < K; k0 += 128) {
        #pragma unroll
        for (int j = 0; j < 4; j++)
            async_copy16b(gA0 + k0 + (size_t)(j * 32) * K, &lds_a[ldsbase + j * 32 * 128]);
        #pragma unroll
        for (int j = 0; j < NF; j++)
            async_copy16b(gB0 + k0 + (size_t)(j * 32) * K, &lds_b[ldsbase + j * 32 * 128]);
        __syncthreads();

        i32x8 bfr[NF];
        #pragma unroll
        for (int j = 0; j < NF; j++) {
            int r = wn * (NF * 16) + j * 16 + lm;
            int s0 = ((2 * q) ^ (r & 7)) * 16, s1 = ((2 * q + 1) ^ (r & 7)) * 16;
            bfr[j] = cat8(*(const i32x4*)&lds_b[r * 128 + s0],
                          *(const i32x4*)&lds_b[r * 128 + s1]);
        }
        #pragma unroll
        for (int i = 0; i < 4; i++) {
            int r = wm * 64 + i * 16 + lm;
            int s0 = ((2 * q) ^ (r & 7)) * 16, s1 = ((2 * q + 1) ^ (r & 7)) * 16;
            i32x8 af = cat8(*(const i32x4*)&lds_a[r * 128 + s0],
                            *(const i32x4*)&lds_a[r * 128 + s1]);
            #pragma unroll
            for (int j = 0; j < NF; j++)
                acc[i][j] = __builtin_amdgcn_mfma_scale_f32_16x16x128_f8f6f4(
                    af, bfr[j], acc[i][j], 0, 0,
                    0, 0x7F7F7F7F, 0, 0x7F7F7F7F);
        }
        __syncthreads();
    }

    // fused per-row rsqrt scale, LDS reused after K-loop
    float* srs = (float*)lds_a;
    if constexpr (EPI == 1) {
        if (tid < 128) {
            const float4* p = (const float4*)&ssq[(size_t)(bm * 128 + tid) * NHEADS];
            float s = 0.f;
            #pragma unroll
            for (int i2 = 0; i2 < 8; i2++) {
                float4 v4 = p[i2];
                s += v4.x + v4.y + v4.z + v4.w;
            }
            srs[tid] = rsqrtf(s * (1.f / D_INNER) + 1e-5f);
        }
        __syncthreads();
    }

    const int row0 = bm * 128 + wm * 64;
    const int col0 = bn * BN + wn * (NF * 16);
    const int lq = (lane >> 4) * 4;
    #pragma unroll
    for (int i = 0; i < 4; i++) {
        #pragma unroll
        for (int j = 0; j < NF; j++) {
            #pragma unroll
            for (int r = 0; r < 4; r++) {
                int gr = row0 + i * 16 + lq + r;
                int gc = col0 + j * 16 + lm;
                float v = acc[i][j][r];
                if constexpr (EPI == 0) {
                    Cb[(size_t)gr * N + gc] = f2b(v * (1.f / WSCALE));
                } else {
                    size_t idx = (size_t)gr * 1024 + gc;
                    float rsv = srs[wm * 64 + i * 16 + lq + r];
                    Cf[idx] = xres[idx] + v * ls[gc] * rsv * (1.f / (WSCALE * YSCALE));
                }
            }
        }
    }
}

// ---------- 5a. conv + chunk-local state; persists conv(B/C), h_local(bf16), dt/cd/scale ----------
__global__ __launch_bounds__(256)
void ssd_hcomp(const unsigned short* __restrict__ zx, const float* __restrict__ dt_bias,
               const float* __restrict__ conv_w, const float* __restrict__ conv_b,
               const float* __restrict__ A_log,
               unsigned short* __restrict__ hbuf, float* __restrict__ pbuf,
               unsigned short* __restrict__ bcg, float* __restrict__ scA) {
    __shared__ unsigned short sXraw[67 * 64];
    __shared__ unsigned short sBCraw[67 * 32];
    __shared__ unsigned short sXT[64 * 72];
    __shared__ unsigned short sBC[64 * 32];
    __shared__ unsigned short sBwT[16 * 72];
    __shared__ float sdt[64], scd[64];

    const int blk = blockIdx.x;
    const int c  = blk & 31;
    const int h  = (blk >> 5) & 31;
    const int b  = blk >> 10;
    const int bh = blk >> 5;
    const int row0 = b * SEQLEN + c * QCHUNK;
    const int batch0 = b * SEQLEN;

    const int t    = threadIdx.x;
    const int w    = t >> 6;
    const int lane = t & 63;
    const int lm   = lane & 15;
    const int lq8  = (lane >> 4) * 8;
    const int lq4  = (lane >> 4) * 4;
    const float Ah = -__expf(A_log[h]);

    // ---- phase 1: halo staging + dt softplus/prefix ----
    for (int i = t; i < 536; i += 256) {
        int r = i >> 3, seg = i & 7;
        int gr = row0 - 3 + r;
        int4 v = (gr >= batch0) ? *(const int4*)&zx[(size_t)gr * NPAD + D_INNER + h * 64 + seg * 8]
                                : (int4){0, 0, 0, 0};
        *(int4*)&sXraw[r * 64 + seg * 8] = v;
    }
    for (int i = t; i < 268; i += 256) {
        int r = i >> 2, seg = i & 3;
        int gr = row0 - 3 + r;
        int4 v = (gr >= batch0) ? *(const int4*)&zx[(size_t)gr * NPAD + 2 * D_INNER + seg * 8]
                                : (int4){0, 0, 0, 0};
        *(int4*)&sBCraw[r * 32 + seg * 8] = v;
    }
    if (t < 64) {
        float raw = b2f(zx[(size_t)(row0 + t) * NPAD + DT_COL + h]) + dt_bias[h];
        float dtv = (raw > 20.f) ? raw : log1pf(__expf(raw));
        float v = dtv;
        #pragma unroll
        for (int o = 1; o < 64; o <<= 1) {
            float u = __shfl_up(v, o, 64);
            if (t >= o) v += u;
        }
        sdt[t] = dtv;
        scd[t] = v;
        float sc = __expf(Ah * v);
        float* scrow = &scA[(size_t)(bh * NCHUNK + c) * 192];
        scrow[t] = dtv; scrow[64 + t] = v; scrow[128 + t] = sc;
        if (t == 63) pbuf[bh * NCHUNK + c] = sc;
    }
    __syncthreads();

    // ---- phase 2: conv + silu (sliding window) ----
    {   // X: thread owns column p, 16 s values
        const int p = t & 63, sblk = (t >> 6) * 16;
        const int ch = h * 64 + p;
        const float4 cw = *(const float4*)&conv_w[ch * 4];
        const float cb = conv_b[ch];
        float x0 = b2f(sXraw[(sblk + 0) * 64 + p]);
        float x1 = b2f(sXraw[(sblk + 1) * 64 + p]);
        float x2 = b2f(sXraw[(sblk + 2) * 64 + p]);
        #pragma unroll
        for (int i = 0; i < 16; i++) {
            float x3 = b2f(sXraw[(sblk + i + 3) * 64 + p]);
            float acc = cb + cw.x * x0 + cw.y * x1 + cw.z * x2 + cw.w * x3;
            float sv = acc / (1.f + __expf(-acc));
            sXT[p * 72 + sblk + i] = f2b(sv);
            x0 = x1; x1 = x2; x2 = x3;
        }
    }
    {   // B/C: thread owns channel ch32, 8 s values; ch32<16 also writes weighted Bw^T
        const int ch32 = t & 31, s0 = (t >> 5) * 8;
        const int ch = D_INNER + ch32;
        const float4 cw = *(const float4*)&conv_w[ch * 4];
        const float cb = conv_b[ch];
        const float cdl = scd[63];
        float x0 = b2f(sBCraw[(s0 + 0) * 32 + ch32]);
        float x1 = b2f(sBCraw[(s0 + 1) * 32 + ch32]);
        float x2 = b2f(sBCraw[(s0 + 2) * 32 + ch32]);
        #pragma unroll
        for (int i = 0; i < 8; i++) {
            int s = s0 + i;
            float x3 = b2f(sBCraw[(s + 3) * 32 + ch32]);
            float acc = cb + cw.x * x0 + cw.y * x1 + cw.z * x2 + cw.w * x3;
            float sv = acc / (1.f + __expf(-acc));
            sBC[s * 32 + ch32] = f2b(sv);
            if (ch32 < 16) {
                float wgt = sdt[s] * __expf(Ah * (cdl - scd[s]));
                sBwT[ch32 * 72 + s] = f2b(sv * wgt);
            }
            x0 = x1; x1 = x2; x2 = x3;
        }
    }
    __syncthreads();

    // ---- phase 3: h_local = Bw^T X  (stored bf16: consumer converts anyway) ----
    f32x4 hacc = (f32x4){0.f, 0.f, 0.f, 0.f};
    #pragma unroll
    for (int ks = 0; ks < 2; ks++) {
        bf16x8 af = *(const bf16x8*)&sBwT[lm * 72 + ks * 32 + lq8];
        bf16x8 bf_ = *(const bf16x8*)&sXT[(w * 16 + lm) * 72 + ks * 32 + lq8];
        hacc = __builtin_amdgcn_mfma_f32_16x16x32_bf16(af, bf_, hacc, 0, 0, 0);
    }
    #pragma unroll
    for (int r = 0; r < 4; r++)
        hbuf[(size_t)(bh * NCHUNK + c) * 1024 + (lq4 + r) * 64 + (w * 16 + lm)] = f2b(hacc[r]);

    if (h == 0) {                        // bcg: 64 rows x 32 ch = 256 int4
        int s = t >> 2, seg = t & 3;
        *(int4*)&bcg[(size_t)(b * SEQLEN + c * 64 + s) * 32 + seg * 8] =
            *(const int4*)&sBC[s * 32 + seg * 8];
    }
}

// ---------- 5b. inter-chunk state scan (bf16 storage, f32 recurrence) ----------
__global__ __launch_bounds__(1024)
void ssd_state_scan(unsigned short* __restrict__ hbuf, const float* __restrict__ pbuf) {
    int bh = blockIdx.x;
    int t = threadIdx.x;
    __shared__ float sP[NCHUNK];
    if (t < NCHUNK) sP[t] = pbuf[bh * NCHUNK + t];
    __syncthreads();
    size_t base = (size_t)bh * NCHUNK * 1024 + t;
    float v[NCHUNK];
    #pragma unroll
    for (int c = 0; c < NCHUNK; c++) v[c] = b2f(hbuf[base + (size_t)c * 1024]);
    float carry = 0.f;
    #pragma unroll
    for (int c = 0; c < NCHUNK; c++) {
        float tmp = v[c];
        v[c] = carry;
        carry = tmp + sP[c] * carry;
    }
    #pragma unroll
    for (int c = 0; c < NCHUNK; c++) hbuf[base + (size_t)c * 1024] = f2b(v[c]);
}

// ---------- 5c. y kernel: recomputes conv(X)+silu locally (no xTg), bf16 h_in ----------
// yq = fp8(YSCALE*(M.X + scale*(C.h_in))*silu(z)); D*x folded into M's diagonal.
// sXraw (conv staging, dead after conv) aliases sM (written after conv) -> no LDS growth.
__global__ __launch_bounds__(256)
void ssd_yfused(const unsigned short* __restrict__ zx,
                const float* __restrict__ conv_w, const float* __restrict__ conv_b,
                const unsigned short* __restrict__ bcg,
                const float* __restrict__ scA,
                const float* __restrict__ A_log, const float* __restrict__ D_param,
                const unsigned short* __restrict__ hbuf,
                unsigned char* __restrict__ y, float* __restrict__ ssq) {
    __shared__ unsigned short sXT[64 * 72];
    __shared__ unsigned short sMX[64 * 72];   // first sXraw[67*64] (8576B), then sM[64*72]
    __shared__ unsigned short sB[64 * 32];
    __shared__ unsigned short sC[64 * 32];
    __shared__ unsigned short sHT[64 * 40];
    __shared__ float sdt[64], scd[64], sSc[64];
    unsigned short* sXraw = sMX;
    unsigned short* sM    = sMX;

    const int blk = blockIdx.x;
    const int c  = blk & 31;
    const int h  = (blk >> 5) & 31;
    const int b  = blk >> 10;
    const int bh = blk >> 5;
    const int row0 = b * SEQLEN + c * QCHUNK;
    const int batch0 = b * SEQLEN;

    const int t    = threadIdx.x;
    const int w    = t >> 6;
    const int lane = t & 63;
    const int lm   = lane & 15;
    const int lq8  = (lane >> 4) * 8;
    const int lq4  = (lane >> 4) * 4;
    const float Ah = -__expf(A_log[h]);

    // ---- z -> registers (exact values the epilogue needs) ----
    unsigned short zreg[4][4];
    #pragma unroll
    for (int r = 0; r < 4; r++)
        #pragma unroll
        for (int pb = 0; pb < 4; pb++)
            zreg[r][pb] = zx[(size_t)(row0 + w * 16 + lq4 + r) * NPAD + h * 64 + pb * 16 + lm];

    // ---- staging ----
    for (int i = t; i < 536; i += 256) {  // X raw (with 3-row halo) for conv recompute
        int r = i >> 3, seg = i & 7;
        int gr = row0 - 3 + r;
        int4 v = (gr >= batch0) ? *(const int4*)&zx[(size_t)gr * NPAD + D_INNER + h * 64 + seg * 8]
                                : (int4){0, 0, 0, 0};
        *(int4*)&sXraw[r * 64 + seg * 8] = v;
    }
    {                                    // B/C: 256 int4
        int s = t >> 2, seg = t & 3;
        int4 v = *(const int4*)&bcg[(size_t)(b * SEQLEN + c * 64 + s) * 32 + seg * 8];
        if (seg < 2) *(int4*)&sB[s * 32 + seg * 8] = v;
        else         *(int4*)&sC[s * 32 + (seg - 2) * 8] = v;
    }
    {                                    // h_in (bf16) -> sHT [p][n]
        size_t hb = (size_t)(bh * NCHUNK + c) * 1024 + (size_t)t * 4;
        const unsigned short* hp = &hbuf[hb];
        int n = t >> 4;
        int p0 = (t * 4) & 63;
        sHT[(p0 + 0) * 40 + n] = hp[0];
        sHT[(p0 + 1) * 40 + n] = hp[1];
        sHT[(p0 + 2) * 40 + n] = hp[2];
        sHT[(p0 + 3) * 40 + n] = hp[3];
    }
    if (t < 64) {                        // pads
        *(int4*)&sB[t * 32 + 16] = (int4){0, 0, 0, 0};
        *(int4*)&sB[t * 32 + 24] = (int4){0, 0, 0, 0};
        *(int4*)&sC[t * 32 + 16] = (int4){0, 0, 0, 0};
        *(int4*)&sC[t * 32 + 24] = (int4){0, 0, 0, 0};
        *(int4*)&sHT[t * 40 + 16] = (int4){0, 0, 0, 0};
        *(int4*)&sHT[t * 40 + 24] = (int4){0, 0, 0, 0};
    }
    if (t < 192) {                       // dt / cd / scale
        float v = scA[(size_t)(bh * NCHUNK + c) * 192 + t];
        if (t < 64) sdt[t] = v;
        else if (t < 128) scd[t - 64] = v;
        else sSc[t - 128] = v;
    }
    __syncthreads();

    // ---- S = C * B^T (lower-triangular blocks) ----
    f32x4 sacc[4];
    {
        bf16x8 cfrag = *(const bf16x8*)&sC[(w * 16 + lm) * 32 + lq8];
        #pragma unroll
        for (int sb = 0; sb < 4; sb++) {
            if (sb <= w) {
                bf16x8 bfrag = *(const bf16x8*)&sB[(sb * 16 + lm) * 32 + lq8];
                sacc[sb] = __builtin_amdgcn_mfma_f32_16x16x32_bf16(
                    cfrag, bfrag, (f32x4){0.f, 0.f, 0.f, 0.f}, 0, 0, 0);
            }
        }
    }
    // ---- conv + silu recompute: sXraw -> sXT (bit-identical to hcomp's) ----
    {
        const int p = t & 63, sblk = (t >> 6) * 16;
        const int ch = h * 64 + p;
        const float4 cw = *(const float4*)&conv_w[ch * 4];
        const float cb = conv_b[ch];
        float x0 = b2f(sXraw[(sblk + 0) * 64 + p]);
        float x1 = b2f(sXraw[(sblk + 1) * 64 + p]);
        float x2 = b2f(sXraw[(sblk + 2) * 64 + p]);
        #pragma unroll
        for (int i = 0; i < 16; i++) {
            float x3 = b2f(sXraw[(sblk + i + 3) * 64 + p]);
            float acc = cb + cw.x * x0 + cw.y * x1 + cw.z * x2 + cw.w * x3;
            float sv = acc / (1.f + __expf(-acc));
            sXT[p * 72 + sblk + i] = f2b(sv);
            x0 = x1; x1 = x2; x2 = x3;
        }
    }
    __syncthreads();   // sXraw reads done (sM may now overwrite); sXT visible to all

    // ---- M[t][s] with D on the diagonal (sM aliases dead sXraw) ----
    const float Dh = D_param[h];
    #pragma unroll
    for (int sb = 0; sb < 4; sb++) {
        int sp = sb * 16 + lm;
        if (sb > w) {
            #pragma unroll
            for (int r = 0; r < 4; r++) sM[(w * 16 + lq4 + r) * 72 + sp] = 0;
        } else {
            float dts = sdt[sp], cds = scd[sp];
            #pragma unroll
            for (int r = 0; r < 4; r++) {
                int tp = w * 16 + lq4 + r;
                float m = 0.f;
                if (sb < w || sp <= tp) {
                    m = sacc[sb][r] * dts * __expf(Ah * (scd[tp] - cds));
                    if (sp == tp) m += Dh;
                }
                sM[tp * 72 + sp] = f2b(m);
            }
        }
    }

    // ---- Y1 = M * X ----
    f32x4 yacc[4];
    #pragma unroll
    for (int pb = 0; pb < 4; pb++) yacc[pb] = (f32x4){0.f, 0.f, 0.f, 0.f};
    #pragma unroll
    for (int ks = 0; ks < 2; ks++) {
        if (ks == 1 && w < 2) continue;
        bf16x8 af = *(const bf16x8*)&sM[(w * 16 + lm) * 72 + ks * 32 + lq8];
        #pragma unroll
        for (int pb = 0; pb < 4; pb++) {
            bf16x8 bf_ = *(const bf16x8*)&sXT[(pb * 16 + lm) * 72 + ks * 32 + lq8];
            yacc[pb] = __builtin_amdgcn_mfma_f32_16x16x32_bf16(af, bf_, yacc[pb], 0, 0, 0);
        }
    }
    // ---- Y2 = C * h_in^T ----
    f32x4 acc2[4];
    {
        bf16x8 cf2 = *(const bf16x8*)&sC[(w * 16 + lm) * 32 + lq8];
        #pragma unroll
        for (int pb = 0; pb < 4; pb++) {
            bf16x8 hf = *(const bf16x8*)&sHT[(pb * 16 + lm) * 40 + lq8];
            acc2[pb] = __builtin_amdgcn_mfma_f32_16x16x32_bf16(
                cf2, hf, (f32x4){0.f, 0.f, 0.f, 0.f}, 0, 0, 0);
        }
    }

    // ---- epilogue: z-gate, fp8 store, ssq partials ----
    #pragma unroll
    for (int r = 0; r < 4; r++) {
        const int tp = w * 16 + lq4 + r;
        const size_t yrow = (size_t)(row0 + tp) * D_INNER + h * 64;
        float ssr = 0.f;
        #pragma unroll
        for (int pb = 0; pb < 4; pb++) {
            int pp = pb * 16 + lm;
            float val = yacc[pb][r] + sSc[tp] * acc2[pb][r];
            float zv = b2f(zreg[r][pb]);
            float yg = val * (zv / (1.f + __expf(-zv)));
            ssr += yg * yg;
            y[yrow + pp] = f2fp8(yg * YSCALE);
        }
        ssr += __shfl_xor(ssr, 1, 16);
        ssr += __shfl_xor(ssr, 2, 16);
        ssr += __shfl_xor(ssr, 4, 16);
        ssr += __shfl_xor(ssr, 8, 16);
        if (lm == 0)
            ssq[(size_t)(row0 + tp) * NHEADS + h] = ssr;
    }
}

// ---------- launcher ----------
extern "C" void kernel_launch(void* const* d_in, const int* in_sizes, int n_in,
                              void* d_out, int out_size, void* d_ws, size_t ws_size,
                              hipStream_t stream) {
    const float* x        = (const float*)d_in[0];
    const float* W_in     = (const float*)d_in[1];
    const float* conv_w   = (const float*)d_in[2];
    const float* conv_b   = (const float*)d_in[3];
    const float* dt_bias  = (const float*)d_in[4];
    const float* A_log    = (const float*)d_in[5];
    const float* D_param  = (const float*)d_in[6];
    const float* norm_w   = (const float*)d_in[7];
    const float* W_out    = (const float*)d_in[8];
    const float* ls       = (const float*)d_in[9];
    float* out = (float*)d_out;

    char* ws = (char*)d_ws;
    size_t off = 0;
    unsigned char*  x_f8  = (unsigned char*)(ws + off);  off += (size_t)MROWS * D_MODEL;       // 8.4 MB
    unsigned char*  winT  = (unsigned char*)(ws + off);  off += (size_t)NPAD * D_MODEL;        // 4.3 MB
    unsigned char*  woutT = (unsigned char*)(ws + off);  off += (size_t)D_MODEL * D_INNER;     // 2.1 MB
    unsigned short* zx    = (unsigned short*)(ws + off); off += (size_t)MROWS * NPAD * 2;      // 69.2 MB
    float*          pbuf  = (float*)(ws + off);          off += (size_t)BATCH * NHEADS * NCHUNK * 4;
    unsigned char*  yb    = (unsigned char*)(ws + off);  off += (size_t)MROWS * D_INNER;       // 16.8 MB
    float*          ssq   = (float*)(ws + off);          off += (size_t)MROWS * NHEADS * 4;    // 1 MB
    unsigned short* hbuf  = (unsigned short*)(ws + off); off += (size_t)BATCH * NHEADS * NCHUNK * 1024 * 2; // 8.4 MB
    unsigned short* bcg   = (unsigned short*)(ws + off); off += (size_t)MROWS * 32 * 2;        // 0.5 MB
    float*          scA   = (float*)(ws + off);          off += (size_t)BATCH * NHEADS * NCHUNK * 192 * 4; // 3.1 MB

    pre_kernel<<<8192 + 1568, 256, 0, stream>>>(x, x_f8, W_in, winT, W_out, woutT, norm_w);
    // in-proj: M=8192, N=4224, K=1024 -> 64 M-tiles x 33 N-tiles = 2112 blocks
    gemm_fp8<0, 4><<<(NPAD / 128) * 64, 256, 0, stream>>>(
        x_f8, winT, D_MODEL, NPAD, zx, nullptr, nullptr, nullptr, nullptr);
    ssd_hcomp<<<BATCH * NHEADS * NCHUNK, 256, 0, stream>>>(
        zx, dt_bias, conv_w, conv_b, A_log, hbuf, pbuf, bcg, scA);
    ssd_state_scan<<<BATCH * NHEADS, 1024, 0, stream>>>(hbuf, pbuf);
    ssd_yfused<<<BATCH * NHEADS * NCHUNK, 256, 0, stream>>>(
        zx, conv_w, conv_b, bcg, scA, A_log, D_param, hbuf, yb, ssq);
    // out-proj: M=8192, N=1024, K=2048, BN=64 -> 64 M-tiles x 16 N-tiles = 1024 blocks
    gemm_fp8<1, 2><<<(D_MODEL / 64) * 64, 256, 0, stream>>>(
        yb, woutT, D_INNER, D_MODEL, nullptr, out, x, ls, ssq);
}